// Round 12
// baseline (1733.504 us; speedup 1.0000x reference)
//
#include <hip/hip_runtime.h>
#include <hip/hip_bf16.h>
#include <math.h>

#define BB   2048
#define LL   60
#define DD   80
#define HH   8
#define HDD  10
#define NLNUM 3
#define NLOC 1187
#define DFF  160
#define IN_DIM 138
#define RELN 119
#define SCS  68   // sc row stride (floats): 68 mod 32 = 4 -> rows spread banks
#define XP   21   // padded tile row stride in float4 (84 words, !=0 mod 32)
#define HP   41   // padded h-tile row stride in float4 (164 words)
#define VP   35   // vin row stride in float4 (140 words)

// Branchless gelu: erf via Abramowitz-Stegun 7.1.26 (|err| <= 1.5e-7).
// Avoids libm erff whose branchy inline blew k_ffn1 to 256 VGPRs + spill.
__device__ __forceinline__ float gelu_f(float a) {
  float x = fabsf(a) * 0.70710678118654752f;
  float t = 1.0f / (1.0f + 0.3275911f * x);
  float y = t * (0.254829592f + t * (-0.284496736f + t * (1.421413741f +
            t * (-1.453152027f + t * 1.061405429f))));
  float e = 1.0f - y * __expf(-x * x);           // erf(|x|)
  float erf_s = copysignf(e, a);
  return 0.5f * a * (1.0f + erf_s);
}

// ---------------------------------------------------------------------------
// K0: pre-transpose rel_emb [l][p:119][d:10] -> relTg [l][d:10][p:120]
// so k_attn stages relT with coalesced float4 loads (was 1190 scattered
// scalars per block x 16384 blocks).
// ---------------------------------------------------------------------------
__global__ __launch_bounds__(256) void k_rprep(
    const float* __restrict__ rel_emb, float* __restrict__ relTg) {
  int idx = blockIdx.x * 256 + threadIdx.x;   // 3*10*120 = 3600
  if (idx >= 3600) return;
  int p = idx % 120;
  int d = (idx / 120) % 10;
  int l = idx / 1200;
  float v = 0.0f;
  if (p < RELN) v = rel_emb[l * RELN * HDD + p * HDD + d];
  relTg[idx] = v;
}

// ---------------------------------------------------------------------------
// K1: embed+inproj+LN as a 48-token GEMM block
// ---------------------------------------------------------------------------
__global__ __launch_bounds__(256) void k_embed(
    const int* __restrict__ loc_seq, const int* __restrict__ user_seq,
    const int* __restrict__ wk_seq, const int* __restrict__ sm_seq,
    const int* __restrict__ dur_seq, const int* __restrict__ diff_seq,
    const float* __restrict__ loc_table, const float* __restrict__ user_table,
    const float* __restrict__ wk_table, const float* __restrict__ hr_table,
    const float* __restrict__ in_w, const float* __restrict__ in_b,
    const float* __restrict__ in_g, const float* __restrict__ in_be,
    const float* __restrict__ pos_emb, float* __restrict__ x) {
  int tok0 = blockIdx.x * 48, tid = threadIdx.x;
  __shared__ __align__(16) float vin[48 * VP * 4];
  __shared__ __align__(16) float ws[140 * 80];
  __shared__ float mstd[96];

  float4* vin4 = (float4*)vin;
  float4* ws4  = (float4*)ws;

  for (int i = tid; i < 140 * 20; i += 256) {
    int r = i / 20, c = i % 20;
    float4 v = make_float4(0.0f, 0.0f, 0.0f, 0.0f);
    if (r < IN_DIM) v = *(const float4*)(in_w + r * 80 + c * 4);
    ws4[i] = v;
  }
  for (int i = tid; i < 48 * 35; i += 256) {
    int t = i / 35, s = i % 35;
    int tok = tok0 + t;
    float4 v;
    if (s < 20) {
      int loc = loc_seq[tok];
      v = *(const float4*)(loc_table + (size_t)loc * 80 + s * 4);
    } else if (s < 26) {
      int usr = user_seq[(tok / LL) * LL];
      v = *(const float4*)(user_table + usr * 24 + (s - 20) * 4);
    } else if (s < 30) {
      int wk = wk_seq[tok];
      v = *(const float4*)(wk_table + wk * 16 + (s - 26) * 4);
    } else if (s < 34) {
      int hr = sm_seq[tok] / 60; hr = min(max(hr, 0), 23);
      v = *(const float4*)(hr_table + hr * 16 + (s - 30) * 4);
    } else {
      v.x = (float)diff_seq[tok] / 10.0f;
      v.y = (float)dur_seq[tok] / 300.0f;
      v.z = 0.0f; v.w = 0.0f;
    }
    vin4[t * VP + s] = v;
  }
  __syncthreads();

  int tg = tid / 20, cg = tid % 20, t0 = tg * 4;
  float acc[4][4] = {};
  if (tid < 240) {
    #pragma unroll 7
    for (int iq = 0; iq < 35; iq++) {
      float4 xv[4], wv[4];
      #pragma unroll
      for (int dt = 0; dt < 4; dt++) xv[dt] = vin4[(t0 + dt) * VP + iq];
      #pragma unroll
      for (int di = 0; di < 4; di++) wv[di] = ws4[(iq * 4 + di) * 20 + cg];
      #pragma unroll
      for (int dt = 0; dt < 4; dt++) {
        const float* xp = (const float*)&xv[dt];
        #pragma unroll
        for (int di = 0; di < 4; di++) {
          const float* wp = (const float*)&wv[di];
          #pragma unroll
          for (int dc = 0; dc < 4; dc++) acc[dt][dc] += xp[di] * wp[dc];
        }
      }
    }
  }
  __syncthreads();
  if (tid < 240) {
    float4 bb = *(const float4*)(in_b + cg * 4);
    const float* bp = (const float*)&bb;
    #pragma unroll
    for (int dt = 0; dt < 4; dt++) {
      float4 y;
      y.x = acc[dt][0] + bp[0];
      y.y = acc[dt][1] + bp[1];
      y.z = acc[dt][2] + bp[2];
      y.w = acc[dt][3] + bp[3];
      vin4[(t0 + dt) * VP + cg] = y;
    }
  }
  __syncthreads();
  if (tid < 48) {
    float s = 0.0f, s2 = 0.0f;
    #pragma unroll
    for (int iq = 0; iq < 20; iq++) {
      float4 v = vin4[tid * VP + iq];
      s  += v.x + v.y + v.z + v.w;
      s2 += v.x * v.x + v.y * v.y + v.z * v.z + v.w * v.w;
    }
    float mean = s / 80.0f;
    float var  = fmaxf(s2 / 80.0f - mean * mean, 0.0f);
    mstd[tid] = mean; mstd[48 + tid] = rsqrtf(var + 1e-5f);
  }
  __syncthreads();
  for (int e = tid; e < 960; e += 256) {
    int t = e / 20, c4 = e % 20;
    float4 v = vin4[t * VP + c4];
    float4 gg = *(const float4*)(in_g + c4 * 4);
    float4 bb = *(const float4*)(in_be + c4 * 4);
    float4 pe = *(const float4*)(pos_emb + ((tok0 + t) % LL) * 80 + c4 * 4);
    float m = mstd[t], r = mstd[48 + t];
    float4 out;
    out.x = (v.x - m) * r * gg.x + bb.x + pe.x;
    out.y = (v.y - m) * r * gg.y + bb.y + pe.y;
    out.z = (v.z - m) * r * gg.z + bb.z + pe.z;
    out.w = (v.w - m) * r * gg.w + bb.w + pe.w;
    ((float4*)(x + (size_t)tok0 * 80))[e] = out;
  }
}

// ---------------------------------------------------------------------------
// K2a: qkv GEMM per batch row b: [60 x 80] @ [80 x 240] -> qkvo[b][c][t]
// ---------------------------------------------------------------------------
__global__ __launch_bounds__(256) void k_qkv(
    const float* __restrict__ x, const float* __restrict__ qkv_w,
    float* __restrict__ qkvo) {
  int b = blockIdx.x, tid = threadIdx.x;
  __shared__ __align__(16) float xs[LL * XP * 4];
  __shared__ __align__(16) float ws[DD * DD];

  const float4* xb4 = (const float4*)(x + (size_t)b * LL * DD);
  float4* xs4 = (float4*)xs;
  for (int i = tid; i < LL * 20; i += 256) xs4[(i / 20) * XP + (i % 20)] = xb4[i];
  float4* ws4 = (float4*)ws;

  for (int c0 = 0; c0 < 240; c0 += 80) {
    __syncthreads();
    for (int i = tid; i < 80 * 20; i += 256)
      ws4[i] = *(const float4*)(qkv_w + (i / 20) * 240 + c0 + (i % 20) * 4);
    __syncthreads();
    for (int slot = tid; slot < 300; slot += 256) {
      int tg = slot / 20, cg = slot % 20;
      int t0 = tg * 4;
      float acc[4][4] = {};
      #pragma unroll
      for (int iq = 0; iq < 20; iq++) {
        float4 xv[4], wv[4];
        #pragma unroll
        for (int dt = 0; dt < 4; dt++) xv[dt] = xs4[(t0 + dt) * XP + iq];
        #pragma unroll
        for (int di = 0; di < 4; di++) wv[di] = ws4[(iq * 4 + di) * 20 + cg];
        #pragma unroll
        for (int dt = 0; dt < 4; dt++) {
          const float* xp = (const float*)&xv[dt];
          #pragma unroll
          for (int di = 0; di < 4; di++) {
            const float* wp = (const float*)&wv[di];
            #pragma unroll
            for (int dc = 0; dc < 4; dc++) acc[dt][dc] += xp[di] * wp[dc];
          }
        }
      }
      float* qb = qkvo + (size_t)b * 14400 + (size_t)(c0 + cg * 4) * 60 + t0;
      #pragma unroll
      for (int dc = 0; dc < 4; dc++)
        *(float4*)(qb + dc * 60) = make_float4(acc[0][dc], acc[1][dc], acc[2][dc], acc[3][dc]);
    }
  }
}

// ---------------------------------------------------------------------------
// K2b: attention — 2 heads sequentially per 256-thread block (8192 blocks).
// Per-head pipeline identical to the tuned round-6 version; relT/msk staged
// once per block (halved vs 1 head/block), relT now coalesced via relTg.
// ---------------------------------------------------------------------------
__global__ __launch_bounds__(256) void k_attn(
    const float* __restrict__ qkvo, const int* __restrict__ loc_seq,
    const float* __restrict__ relTg,   // layer slice [10][120]
    float* __restrict__ o) {
  int blk = blockIdx.x;
  int b = blk >> 2, hp = (blk & 3) << 1;
  int tid = threadIdx.x;

  __shared__ __align__(16) float qs[HDD * 60];
  __shared__ __align__(16) float ks[HDD * 60];
  __shared__ __align__(16) float vs[HDD * 60];
  __shared__ __align__(16) float relT[HDD * 120];
  __shared__ __align__(16) float sc[60 * SCS];
  __shared__ __align__(16) float rsum[64];
  __shared__ float msk[60];

  const float4* src = (const float4*)(qkvo + (size_t)b * 14400);
  const float4* rg4 = (const float4*)relTg;
  float4* relT4 = (float4*)relT;
  for (int i = tid; i < 300; i += 256) relT4[i] = rg4[i];
  if (tid < 60) msk[tid] = (loc_seq[b * LL + tid] == 0) ? 1.0f : 0.0f;

  for (int hh = 0; hh < 2; hh++) {
    int h = hp + hh;
    __syncthreads();   // prior head's AV reads done (and relT/msk staged)
    // stage q/k/v for this head: 450 coalesced f4
    float4* q4 = (float4*)qs; float4* k4 = (float4*)ks; float4* v4 = (float4*)vs;
    for (int i = tid; i < 450; i += 256) {
      int part = i / 150, ii = i % 150;
      float4 v = src[part * 1200 + h * 150 + ii];
      if (part == 0) q4[ii] = v;
      else if (part == 1) k4[ii] = v;
      else v4[ii] = v;
    }
    __syncthreads();

    // scores
    if (tid < 225) {
      int ig = tid / 15, jg = tid % 15;
      int i0 = ig * 4, j0 = jg * 4;
      int w0 = j0 - i0 + 56;
      float acc[4][4] = {};
      #pragma unroll
      for (int d = 0; d < 10; d++) {
        float4 qv = *(const float4*)(qs + d * 60 + i0);
        float4 kv = *(const float4*)(ks + d * 60 + j0);
        float4 rA = *(const float4*)(relT + d * 120 + w0);
        float4 rB = *(const float4*)(relT + d * 120 + w0 + 4);
        float rr[8] = {rA.x, rA.y, rA.z, rA.w, rB.x, rB.y, rB.z, rB.w};
        const float* qp = (const float*)&qv;
        const float* kp = (const float*)&kv;
        #pragma unroll
        for (int di = 0; di < 4; di++)
          #pragma unroll
          for (int dj = 0; dj < 4; dj++)
            acc[di][dj] += qp[di] * (kp[dj] + rr[dj - di + 3]);
      }
      const float scale = 0.31622776601683794f;
      #pragma unroll
      for (int di = 0; di < 4; di++) {
        #pragma unroll
        for (int dj = 0; dj < 4; dj++) {
          float v = acc[di][dj] * scale;
          if (msk[j0 + dj] != 0.0f) v = -1e30f;
          acc[di][dj] = v;
        }
        *(float4*)(sc + (i0 + di) * SCS + j0) =
            make_float4(acc[di][0], acc[di][1], acc[di][2], acc[di][3]);
      }
    }
    __syncthreads();

    // per-thread-row softmax
    if (tid < 60) {
      float* row = sc + tid * SCS;
      int c = (tid >> 3) & 7;
      float m0 = -3.0e38f, m1 = -3.0e38f, m2 = -3.0e38f, m3 = -3.0e38f;
      #pragma unroll
      for (int s = 0; s < 15; s++) {
        int k = c + s; if (k >= 15) k -= 15;
        float4 v = *(const float4*)(row + 4 * k);
        m0 = fmaxf(m0, v.x); m1 = fmaxf(m1, v.y);
        m2 = fmaxf(m2, v.z); m3 = fmaxf(m3, v.w);
      }
      float m = fmaxf(fmaxf(m0, m1), fmaxf(m2, m3));
      float s0 = 0.0f, s1 = 0.0f, s2 = 0.0f, s3 = 0.0f;
      #pragma unroll
      for (int s = 0; s < 15; s++) {
        int k = c + s; if (k >= 15) k -= 15;
        float4 v = *(float4*)(row + 4 * k);
        v.x = __expf(v.x - m); v.y = __expf(v.y - m);
        v.z = __expf(v.z - m); v.w = __expf(v.w - m);
        *(float4*)(row + 4 * k) = v;
        s0 += v.x; s1 += v.y; s2 += v.z; s3 += v.w;
      }
      rsum[tid] = 1.0f / (s0 + s1 + s2 + s3);
    }
    __syncthreads();

    // AV
    if (tid < 150) {
      int ig = tid / 10, d = tid % 10;
      float acc[4] = {0, 0, 0, 0};
      #pragma unroll 5
      for (int jq = 0; jq < 15; jq++) {
        float4 vv = *(const float4*)(vs + d * 60 + jq * 4);
        #pragma unroll
        for (int di = 0; di < 4; di++) {
          float4 av = *(const float4*)(sc + (ig + 15 * di) * SCS + jq * 4);
          acc[di] += av.x * vv.x + av.y * vv.y + av.z * vv.z + av.w * vv.w;
        }
      }
      #pragma unroll
      for (int di = 0; di < 4; di++) {
        float r = rsum[ig + 15 * di];
        o[((size_t)b * 60 + ig + 15 * di) * 80 + h * 10 + d] = acc[di] * r;
      }
    }
  }
}

// ---------------------------------------------------------------------------
// K3: x = LN(x + o @ proj_w + proj_b)  — 48 tokens/block
// ---------------------------------------------------------------------------
__global__ __launch_bounds__(256) void k_proj_ln(
    const float* __restrict__ o, const float* __restrict__ proj_w,
    const float* __restrict__ proj_b, const float* __restrict__ g,
    const float* __restrict__ be, float* __restrict__ x) {
  int tok0 = blockIdx.x * 48, tid = threadIdx.x;
  __shared__ __align__(16) float os[48 * XP * 4];
  __shared__ __align__(16) float ws[80 * 80];
  __shared__ float mstd[96];

  float4* os4 = (float4*)os;
  const float4* ob4 = (const float4*)(o + (size_t)tok0 * 80);
  for (int i = tid; i < 960; i += 256) os4[(i / 20) * XP + (i % 20)] = ob4[i];
  float4* ws4 = (float4*)ws;
  for (int i = tid; i < 1600; i += 256)
    ws4[i] = *(const float4*)(proj_w + (i / 20) * 80 + (i % 20) * 4);
  __syncthreads();

  int tg = tid / 20, cg = tid % 20, t0 = tg * 4;
  float acc[4][4] = {};
  if (tid < 240) {
    #pragma unroll
    for (int iq = 0; iq < 20; iq++) {
      float4 xv[4], wv[4];
      #pragma unroll
      for (int dt = 0; dt < 4; dt++) xv[dt] = os4[(t0 + dt) * XP + iq];
      #pragma unroll
      for (int di = 0; di < 4; di++) wv[di] = ws4[(iq * 4 + di) * 20 + cg];
      #pragma unroll
      for (int dt = 0; dt < 4; dt++) {
        const float* xp = (const float*)&xv[dt];
        #pragma unroll
        for (int di = 0; di < 4; di++) {
          const float* wp = (const float*)&wv[di];
          #pragma unroll
          for (int dc = 0; dc < 4; dc++) acc[dt][dc] += xp[di] * wp[dc];
        }
      }
    }
  }
  __syncthreads();
  if (tid < 240) {
    float4 pb = *(const float4*)(proj_b + cg * 4);
    const float* pbp = (const float*)&pb;
    #pragma unroll
    for (int dt = 0; dt < 4; dt++) {
      float4 xr = *(const float4*)(x + (size_t)(tok0 + t0 + dt) * 80 + cg * 4);
      const float* xrp = (const float*)&xr;
      float4 out;
      out.x = acc[dt][0] + pbp[0] + xrp[0];
      out.y = acc[dt][1] + pbp[1] + xrp[1];
      out.z = acc[dt][2] + pbp[2] + xrp[2];
      out.w = acc[dt][3] + pbp[3] + xrp[3];
      os4[(t0 + dt) * XP + cg] = out;
    }
  }
  __syncthreads();
  if (tid < 48) {
    float s = 0.0f, s2 = 0.0f;
    #pragma unroll
    for (int iq = 0; iq < 20; iq++) {
      float4 v = os4[tid * XP + iq];
      s  += v.x + v.y + v.z + v.w;
      s2 += v.x * v.x + v.y * v.y + v.z * v.z + v.w * v.w;
    }
    float mean = s / 80.0f;
    float var  = fmaxf(s2 / 80.0f - mean * mean, 0.0f);
    mstd[tid] = mean; mstd[48 + tid] = rsqrtf(var + 1e-5f);
  }
  __syncthreads();
  for (int e = tid; e < 960; e += 256) {
    int t = e / 20, c4 = e % 20;
    float4 v = os4[t * XP + c4];
    float4 gg = *(const float4*)(g + c4 * 4);
    float4 bb = *(const float4*)(be + c4 * 4);
    float m = mstd[t], r = mstd[48 + t];
    float4 out;
    out.x = (v.x - m) * r * gg.x + bb.x;
    out.y = (v.y - m) * r * gg.y + bb.y;
    out.z = (v.z - m) * r * gg.z + bb.z;
    out.w = (v.w - m) * r * gg.w + bb.w;
    ((float4*)(x + (size_t)tok0 * 80))[e] = out;
  }
}

// ---------------------------------------------------------------------------
// K4: fused FFN: x = LN(x + W2ᵀgelu(W1ᵀx + b1) + b2)  — 48 tokens/block
// ---------------------------------------------------------------------------
__global__ __launch_bounds__(256) void k_ffn(
    const float* __restrict__ w1, const float* __restrict__ b1,
    const float* __restrict__ w2, const float* __restrict__ b2,
    const float* __restrict__ g, const float* __restrict__ be,
    float* __restrict__ x) {
  int tok0 = blockIdx.x * 48, tid = threadIdx.x;
  __shared__ __align__(16) float xs[48 * XP * 4];
  __shared__ __align__(16) float hs[48 * HP * 4];
  __shared__ __align__(16) float ws[80 * 80];
  __shared__ float mstd[96];

  float4* xs4 = (float4*)xs;
  float4* hs4 = (float4*)hs;
  float4* ws4 = (float4*)ws;
  const float4* xb4 = (const float4*)(x + (size_t)tok0 * 80);
  for (int i = tid; i < 960; i += 256) xs4[(i / 20) * XP + (i % 20)] = xb4[i];

  int tg = tid / 20, cg = tid % 20, t0 = tg * 4;

  for (int c0 = 0; c0 < 160; c0 += 80) {
    __syncthreads();
    for (int i = tid; i < 1600; i += 256)
      ws4[i] = *(const float4*)(w1 + (i / 20) * 160 + c0 + (i % 20) * 4);
    __syncthreads();
    if (tid < 240) {
      float acc[4][4] = {};
      #pragma unroll
      for (int iq = 0; iq < 20; iq++) {
        float4 xv[4], wv[4];
        #pragma unroll
        for (int dt = 0; dt < 4; dt++) xv[dt] = xs4[(t0 + dt) * XP + iq];
        #pragma unroll
        for (int di = 0; di < 4; di++) wv[di] = ws4[(iq * 4 + di) * 20 + cg];
        #pragma unroll
        for (int dt = 0; dt < 4; dt++) {
          const float* xp = (const float*)&xv[dt];
          #pragma unroll
          for (int di = 0; di < 4; di++) {
            const float* wp = (const float*)&wv[di];
            #pragma unroll
            for (int dc = 0; dc < 4; dc++) acc[dt][dc] += xp[di] * wp[dc];
          }
        }
      }
      float4 bb = *(const float4*)(b1 + c0 + cg * 4);
      const float* bp = (const float*)&bb;
      #pragma unroll
      for (int dt = 0; dt < 4; dt++) {
        float4 out;
        float* op = (float*)&out;
        #pragma unroll
        for (int dc = 0; dc < 4; dc++)
          op[dc] = gelu_f(acc[dt][dc] + bp[dc]);
        hs4[(t0 + dt) * HP + c0 / 4 + cg] = out;
      }
    }
  }

  float acc[4][4] = {};
  for (int k0 = 0; k0 < 160; k0 += 80) {
    __syncthreads();
    for (int i = tid; i < 1600; i += 256)
      ws4[i] = *(const float4*)(w2 + (size_t)(k0 + i / 20) * 80 + (i % 20) * 4);
    __syncthreads();
    if (tid < 240) {
      #pragma unroll
      for (int iq = 0; iq < 20; iq++) {
        float4 hv[4], wv[4];
        #pragma unroll
        for (int dt = 0; dt < 4; dt++) hv[dt] = hs4[(t0 + dt) * HP + k0 / 4 + iq];
        #pragma unroll
        for (int di = 0; di < 4; di++) wv[di] = ws4[(iq * 4 + di) * 20 + cg];
        #pragma unroll
        for (int dt = 0; dt < 4; dt++) {
          const float* hp = (const float*)&hv[dt];
          #pragma unroll
          for (int di = 0; di < 4; di++) {
            const float* wp = (const float*)&wv[di];
            #pragma unroll
            for (int dc = 0; dc < 4; dc++) acc[dt][dc] += hp[di] * wp[dc];
          }
        }
      }
    }
  }
  __syncthreads();
  if (tid < 240) {
    float4 bb = *(const float4*)(b2 + cg * 4);
    const float* bp = (const float*)&bb;
    #pragma unroll
    for (int dt = 0; dt < 4; dt++) {
      float4 xr = xs4[(t0 + dt) * XP + cg];
      const float* xrp = (const float*)&xr;
      float4 out;
      out.x = acc[dt][0] + bp[0] + xrp[0];
      out.y = acc[dt][1] + bp[1] + xrp[1];
      out.z = acc[dt][2] + bp[2] + xrp[2];
      out.w = acc[dt][3] + bp[3] + xrp[3];
      hs4[(t0 + dt) * HP + cg] = out;
    }
  }
  __syncthreads();
  if (tid < 48) {
    float s = 0.0f, s2 = 0.0f;
    #pragma unroll
    for (int iq = 0; iq < 20; iq++) {
      float4 v = hs4[tid * HP + iq];
      s  += v.x + v.y + v.z + v.w;
      s2 += v.x * v.x + v.y * v.y + v.z * v.z + v.w * v.w;
    }
    float mean = s / 80.0f;
    float var  = fmaxf(s2 / 80.0f - mean * mean, 0.0f);
    mstd[tid] = mean; mstd[48 + tid] = rsqrtf(var + 1e-5f);
  }
  __syncthreads();
  for (int e = tid; e < 960; e += 256) {
    int t = e / 20, c4 = e % 20;
    float4 v = hs4[t * HP + c4];
    float4 gg = *(const float4*)(g + c4 * 4);
    float4 bb = *(const float4*)(be + c4 * 4);
    float m = mstd[t], r = mstd[48 + t];
    float4 out;
    out.x = (v.x - m) * r * gg.x + bb.x;
    out.y = (v.y - m) * r * gg.y + bb.y;
    out.z = (v.z - m) * r * gg.z + bb.z;
    out.w = (v.w - m) * r * gg.w + bb.w;
    ((float4*)(x + (size_t)tok0 * 80))[e] = out;
  }
}

// ---------------------------------------------------------------------------
// K5: final LN at gathered position + fnorm + h1 = gelu(final@pr_w1+pr_b1)
// ---------------------------------------------------------------------------
__global__ __launch_bounds__(128) void k_final(
    const float* __restrict__ x, const int* __restrict__ seq_len,
    const float* __restrict__ fn_g, const float* __restrict__ fn_b,
    const float* __restrict__ pr_w1, const float* __restrict__ pr_b1,
    float* __restrict__ fnorm, float* __restrict__ h1) {
  int b = blockIdx.x, tid = threadIdx.x;
  __shared__ float red[128], red2[128];
  __shared__ float fbuf[DD];
  int t = seq_len[b] - 1; t = min(max(t, 0), LL - 1);
  float v = 0.0f;
  if (tid < DD) v = x[((size_t)b * LL + t) * DD + tid];
  red[tid]  = (tid < DD) ? v : 0.0f;
  red2[tid] = (tid < DD) ? v * v : 0.0f;
  __syncthreads();
  for (int s = 64; s > 0; s >>= 1) {
    if (tid < s) { red[tid] += red[tid + s]; red2[tid] += red2[tid + s]; }
    __syncthreads();
  }
  float mean = red[0] / DD;
  float var  = fmaxf(red2[0] / DD - mean * mean, 0.0f);
  float rstd = rsqrtf(var + 1e-5f);
  float f = 0.0f;
  if (tid < DD) { f = (v - mean) * rstd * fn_g[tid] + fn_b[tid]; fbuf[tid] = f; }
  __syncthreads();
  red[tid] = (tid < DD) ? f * f : 0.0f;
  __syncthreads();
  for (int s = 64; s > 0; s >>= 1) {
    if (tid < s) red[tid] += red[tid + s];
    __syncthreads();
  }
  float rn = 1.0f / fmaxf(sqrtf(red[0]), 1e-12f);
  if (tid < DD) {
    fnorm[(size_t)b * DD + tid] = f * rn;
    float gacc = pr_b1[tid];
    for (int i = 0; i < DD; i++) gacc += fbuf[i] * pr_w1[i * DD + tid];
    h1[(size_t)b * DD + tid] = gelu_f(gacc);
  }
}

// ---------------------------------------------------------------------------
// K6: normalize proto rows -> transposed pnormT[k][c]
// ---------------------------------------------------------------------------
__global__ __launch_bounds__(128) void k_pnorm(
    const float* __restrict__ protos, float* __restrict__ pnormT) {
  int c = blockIdx.x, tid = threadIdx.x;
  __shared__ float red[128];
  float v = 0.0f;
  if (tid < DD) v = protos[(size_t)c * DD + tid];
  red[tid] = (tid < DD) ? v * v : 0.0f;
  __syncthreads();
  for (int s = 64; s > 0; s >>= 1) {
    if (tid < s) red[tid] += red[tid + s];
    __syncthreads();
  }
  float rn = 1.0f / fmaxf(sqrtf(red[0]), 1e-12f);
  if (tid < DD) pnormT[(size_t)tid * NLOC + c] = v * rn;
}

// ---------------------------------------------------------------------------
// K7: logits — 4 batch rows per block
// ---------------------------------------------------------------------------
__global__ __launch_bounds__(256) void k_logits(
    const float* __restrict__ h1, const float* __restrict__ fnorm,
    const float* __restrict__ pr_w2, const float* __restrict__ pr_b2,
    const float* __restrict__ pnormT, const float* __restrict__ temp,
    float* __restrict__ out) {
  int b0 = (blockIdx.x / 5) * 4, cb = blockIdx.x % 5;
  int tid = threadIdx.x;
  int c = cb * 256 + tid;
  __shared__ float h1s[4][DD], fns[4][DD];
  for (int i = tid; i < 4 * DD; i += 256) {
    int j = i / DD, k = i % DD;
    h1s[j][k] = h1[(size_t)(b0 + j) * DD + k];
    fns[j][k] = fnorm[(size_t)(b0 + j) * DD + k];
  }
  __syncthreads();
  if (c < NLOC) {
    float a1[4] = {0, 0, 0, 0}, a2[4] = {0, 0, 0, 0};
    for (int k = 0; k < DD; k++) {
      float w = pr_w2[(size_t)k * NLOC + c];
      float p = pnormT[(size_t)k * NLOC + c];
      #pragma unroll
      for (int j = 0; j < 4; j++) {
        a1[j] += h1s[j][k] * w;
        a2[j] += fns[j][k] * p;
      }
    }
    float pb = pr_b2[c];
    float tt = fminf(fmaxf(temp[0], 0.5f), 3.0f);
    #pragma unroll
    for (int j = 0; j < 4; j++)
      out[(size_t)(b0 + j) * NLOC + c] = (0.5f * (a1[j] + pb) + 7.5f * a2[j]) / tt;
  }
}

// ---------------------------------------------------------------------------
extern "C" void kernel_launch(void* const* d_in, const int* in_sizes, int n_in,
                              void* d_out, int out_size, void* d_ws, size_t ws_size,
                              hipStream_t stream) {
  const int* loc_seq   = (const int*)d_in[0];
  const int* user_seq  = (const int*)d_in[1];
  const int* wk_seq    = (const int*)d_in[2];
  const int* sm_seq    = (const int*)d_in[3];
  const int* dur_seq   = (const int*)d_in[4];
  const int* diff_seq  = (const int*)d_in[5];
  const int* seq_len   = (const int*)d_in[6];
  const float* loc_table = (const float*)d_in[7];
  const float* user_table= (const float*)d_in[8];
  const float* wk_table  = (const float*)d_in[9];
  const float* hr_table  = (const float*)d_in[10];
  const float* in_w   = (const float*)d_in[11];
  const float* in_b   = (const float*)d_in[12];
  const float* in_g   = (const float*)d_in[13];
  const float* in_be  = (const float*)d_in[14];
  const float* pos_emb= (const float*)d_in[15];
  const float* qkv_w  = (const float*)d_in[16];
  const float* proj_w = (const float*)d_in[17];
  const float* proj_b = (const float*)d_in[18];
  const float* rel_emb= (const float*)d_in[19];
  const float* n1_g   = (const float*)d_in[20];
  const float* n1_b   = (const float*)d_in[21];
  const float* ffn_w1 = (const float*)d_in[22];
  const float* ffn_b1 = (const float*)d_in[23];
  const float* ffn_w2 = (const float*)d_in[24];
  const float* ffn_b2 = (const float*)d_in[25];
  const float* n2_g   = (const float*)d_in[26];
  const float* n2_b   = (const float*)d_in[27];
  const float* fn_g   = (const float*)d_in[28];
  const float* fn_b   = (const float*)d_in[29];
  const float* pr_w1  = (const float*)d_in[30];
  const float* pr_b1  = (const float*)d_in[31];
  const float* pr_w2  = (const float*)d_in[32];
  const float* pr_b2  = (const float*)d_in[33];
  const float* protos = (const float*)d_in[34];
  const float* temp   = (const float*)d_in[35];
  float* out = (float*)d_out;

  float* x      = (float*)d_ws;
  float* o      = x + (size_t)BB * LL * DD;
  float* qkvo   = o + (size_t)BB * LL * DD;
  float* fnorm  = qkvo + (size_t)BB * 14400;
  float* h1     = fnorm + (size_t)BB * DD;
  float* pnormT = h1 + (size_t)BB * DD;
  float* relTg  = pnormT + (size_t)DD * NLOC;   // 3600 floats

  k_rprep<<<15, 256, 0, stream>>>(rel_emb, relTg);

  k_embed<<<BB * LL / 48, 256, 0, stream>>>(loc_seq, user_seq, wk_seq, sm_seq,
                                            dur_seq, diff_seq, loc_table,
                                            user_table, wk_table, hr_table,
                                            in_w, in_b, in_g, in_be, pos_emb, x);

  for (int l = 0; l < NLNUM; l++) {
    k_qkv<<<BB, 256, 0, stream>>>(x, qkv_w + (size_t)l * 80 * 240, qkvo);
    k_attn<<<BB * 4, 256, 0, stream>>>(qkvo, loc_seq, relTg + (size_t)l * 1200, o);
    k_proj_ln<<<BB * LL / 48, 256, 0, stream>>>(o, proj_w + (size_t)l * DD * DD,
                                                proj_b + (size_t)l * DD,
                                                n1_g + (size_t)l * DD,
                                                n1_b + (size_t)l * DD, x);
    k_ffn<<<BB * LL / 48, 256, 0, stream>>>(ffn_w1 + (size_t)l * DD * DFF,
                                            ffn_b1 + (size_t)l * DFF,
                                            ffn_w2 + (size_t)l * DFF * DD,
                                            ffn_b2 + (size_t)l * DD,
                                            n2_g + (size_t)l * DD,
                                            n2_b + (size_t)l * DD, x);
  }

  k_pnorm<<<NLOC, 128, 0, stream>>>(protos, pnormT);
  k_final<<<BB, 128, 0, stream>>>(x, seq_len, fn_g, fn_b, pr_w1, pr_b1, fnorm, h1);
  k_logits<<<(BB / 4) * 5, 256, 0, stream>>>(h1, fnorm, pr_w2, pr_b2, pnormT, temp, out);
}

// Round 13
// 1639.134 us; speedup vs baseline: 1.0576x; 1.0576x over previous
//
#include <hip/hip_runtime.h>
#include <hip/hip_bf16.h>
#include <math.h>

#define BB   2048
#define LL   60
#define DD   80
#define HH   8
#define HDD  10
#define NLNUM 3
#define NLOC 1187
#define DFF  160
#define IN_DIM 138
#define RELN 119
#define SCS  68   // sc row stride (floats): 68 mod 32 = 4 -> rows spread banks
#define XP   21   // padded tile row stride in float4 (84 words, !=0 mod 32)
#define HP   41   // padded h-tile row stride in float4 (164 words)
#define VP   35   // vin row stride in float4 (140 words)

// Branchless gelu: erf via Abramowitz-Stegun 7.1.26 (|err| <= 1.5e-7).
// Avoids libm erff whose branchy inline blew k_ffn1 to 256 VGPRs + spill.
__device__ __forceinline__ float gelu_f(float a) {
  float x = fabsf(a) * 0.70710678118654752f;
  float t = 1.0f / (1.0f + 0.3275911f * x);
  float y = t * (0.254829592f + t * (-0.284496736f + t * (1.421413741f +
            t * (-1.453152027f + t * 1.061405429f))));
  float e = 1.0f - y * __expf(-x * x);           // erf(|x|)
  float erf_s = copysignf(e, a);
  return 0.5f * a * (1.0f + erf_s);
}

// ---------------------------------------------------------------------------
// K0: pre-transpose rel_emb [l][p:119][d:10] -> relTg [l][d:10][p:120]
// so k_attn stages relT with 300 coalesced float4 loads instead of 1190
// scattered scalars (x 16384 blocks x 3 layers).
// ---------------------------------------------------------------------------
__global__ __launch_bounds__(256) void k_rprep(
    const float* __restrict__ rel_emb, float* __restrict__ relTg) {
  int idx = blockIdx.x * 256 + threadIdx.x;   // 3*10*120 = 3600
  if (idx >= 3600) return;
  int p = idx % 120;
  int d = (idx / 120) % 10;
  int l = idx / 1200;
  float v = 0.0f;
  if (p < RELN) v = rel_emb[l * RELN * HDD + p * HDD + d];
  relTg[idx] = v;
}

// ---------------------------------------------------------------------------
// K1: embed+inproj+LN as a 48-token GEMM block
// ---------------------------------------------------------------------------
__global__ __launch_bounds__(256) void k_embed(
    const int* __restrict__ loc_seq, const int* __restrict__ user_seq,
    const int* __restrict__ wk_seq, const int* __restrict__ sm_seq,
    const int* __restrict__ dur_seq, const int* __restrict__ diff_seq,
    const float* __restrict__ loc_table, const float* __restrict__ user_table,
    const float* __restrict__ wk_table, const float* __restrict__ hr_table,
    const float* __restrict__ in_w, const float* __restrict__ in_b,
    const float* __restrict__ in_g, const float* __restrict__ in_be,
    const float* __restrict__ pos_emb, float* __restrict__ x) {
  int tok0 = blockIdx.x * 48, tid = threadIdx.x;
  __shared__ __align__(16) float vin[48 * VP * 4];
  __shared__ __align__(16) float ws[140 * 80];
  __shared__ float mstd[96];

  float4* vin4 = (float4*)vin;
  float4* ws4  = (float4*)ws;

  for (int i = tid; i < 140 * 20; i += 256) {
    int r = i / 20, c = i % 20;
    float4 v = make_float4(0.0f, 0.0f, 0.0f, 0.0f);
    if (r < IN_DIM) v = *(const float4*)(in_w + r * 80 + c * 4);
    ws4[i] = v;
  }
  for (int i = tid; i < 48 * 35; i += 256) {
    int t = i / 35, s = i % 35;
    int tok = tok0 + t;
    float4 v;
    if (s < 20) {
      int loc = loc_seq[tok];
      v = *(const float4*)(loc_table + (size_t)loc * 80 + s * 4);
    } else if (s < 26) {
      int usr = user_seq[(tok / LL) * LL];
      v = *(const float4*)(user_table + usr * 24 + (s - 20) * 4);
    } else if (s < 30) {
      int wk = wk_seq[tok];
      v = *(const float4*)(wk_table + wk * 16 + (s - 26) * 4);
    } else if (s < 34) {
      int hr = sm_seq[tok] / 60; hr = min(max(hr, 0), 23);
      v = *(const float4*)(hr_table + hr * 16 + (s - 30) * 4);
    } else {
      v.x = (float)diff_seq[tok] / 10.0f;
      v.y = (float)dur_seq[tok] / 300.0f;
      v.z = 0.0f; v.w = 0.0f;
    }
    vin4[t * VP + s] = v;
  }
  __syncthreads();

  int tg = tid / 20, cg = tid % 20, t0 = tg * 4;
  float acc[4][4] = {};
  if (tid < 240) {
    #pragma unroll 7
    for (int iq = 0; iq < 35; iq++) {
      float4 xv[4], wv[4];
      #pragma unroll
      for (int dt = 0; dt < 4; dt++) xv[dt] = vin4[(t0 + dt) * VP + iq];
      #pragma unroll
      for (int di = 0; di < 4; di++) wv[di] = ws4[(iq * 4 + di) * 20 + cg];
      #pragma unroll
      for (int dt = 0; dt < 4; dt++) {
        const float* xp = (const float*)&xv[dt];
        #pragma unroll
        for (int di = 0; di < 4; di++) {
          const float* wp = (const float*)&wv[di];
          #pragma unroll
          for (int dc = 0; dc < 4; dc++) acc[dt][dc] += xp[di] * wp[dc];
        }
      }
    }
  }
  __syncthreads();
  if (tid < 240) {
    float4 bb = *(const float4*)(in_b + cg * 4);
    const float* bp = (const float*)&bb;
    #pragma unroll
    for (int dt = 0; dt < 4; dt++) {
      float4 y;
      y.x = acc[dt][0] + bp[0];
      y.y = acc[dt][1] + bp[1];
      y.z = acc[dt][2] + bp[2];
      y.w = acc[dt][3] + bp[3];
      vin4[(t0 + dt) * VP + cg] = y;
    }
  }
  __syncthreads();
  if (tid < 48) {
    float s = 0.0f, s2 = 0.0f;
    #pragma unroll
    for (int iq = 0; iq < 20; iq++) {
      float4 v = vin4[tid * VP + iq];
      s  += v.x + v.y + v.z + v.w;
      s2 += v.x * v.x + v.y * v.y + v.z * v.z + v.w * v.w;
    }
    float mean = s / 80.0f;
    float var  = fmaxf(s2 / 80.0f - mean * mean, 0.0f);
    mstd[tid] = mean; mstd[48 + tid] = rsqrtf(var + 1e-5f);
  }
  __syncthreads();
  for (int e = tid; e < 960; e += 256) {
    int t = e / 20, c4 = e % 20;
    float4 v = vin4[t * VP + c4];
    float4 gg = *(const float4*)(in_g + c4 * 4);
    float4 bb = *(const float4*)(in_be + c4 * 4);
    float4 pe = *(const float4*)(pos_emb + ((tok0 + t) % LL) * 80 + c4 * 4);
    float m = mstd[t], r = mstd[48 + t];
    float4 out;
    out.x = (v.x - m) * r * gg.x + bb.x + pe.x;
    out.y = (v.y - m) * r * gg.y + bb.y + pe.y;
    out.z = (v.z - m) * r * gg.z + bb.z + pe.z;
    out.w = (v.w - m) * r * gg.w + bb.w + pe.w;
    ((float4*)(x + (size_t)tok0 * 80))[e] = out;
  }
}

// ---------------------------------------------------------------------------
// K2a: qkv GEMM per batch row b: [60 x 80] @ [80 x 240] -> qkvo[b][c][t]
// ---------------------------------------------------------------------------
__global__ __launch_bounds__(256) void k_qkv(
    const float* __restrict__ x, const float* __restrict__ qkv_w,
    float* __restrict__ qkvo) {
  int b = blockIdx.x, tid = threadIdx.x;
  __shared__ __align__(16) float xs[LL * XP * 4];
  __shared__ __align__(16) float ws[DD * DD];

  const float4* xb4 = (const float4*)(x + (size_t)b * LL * DD);
  float4* xs4 = (float4*)xs;
  for (int i = tid; i < LL * 20; i += 256) xs4[(i / 20) * XP + (i % 20)] = xb4[i];
  float4* ws4 = (float4*)ws;

  for (int c0 = 0; c0 < 240; c0 += 80) {
    __syncthreads();
    for (int i = tid; i < 80 * 20; i += 256)
      ws4[i] = *(const float4*)(qkv_w + (i / 20) * 240 + c0 + (i % 20) * 4);
    __syncthreads();
    for (int slot = tid; slot < 300; slot += 256) {
      int tg = slot / 20, cg = slot % 20;
      int t0 = tg * 4;
      float acc[4][4] = {};
      #pragma unroll
      for (int iq = 0; iq < 20; iq++) {
        float4 xv[4], wv[4];
        #pragma unroll
        for (int dt = 0; dt < 4; dt++) xv[dt] = xs4[(t0 + dt) * XP + iq];
        #pragma unroll
        for (int di = 0; di < 4; di++) wv[di] = ws4[(iq * 4 + di) * 20 + cg];
        #pragma unroll
        for (int dt = 0; dt < 4; dt++) {
          const float* xp = (const float*)&xv[dt];
          #pragma unroll
          for (int di = 0; di < 4; di++) {
            const float* wp = (const float*)&wv[di];
            #pragma unroll
            for (int dc = 0; dc < 4; dc++) acc[dt][dc] += xp[di] * wp[dc];
          }
        }
      }
      float* qb = qkvo + (size_t)b * 14400 + (size_t)(c0 + cg * 4) * 60 + t0;
      #pragma unroll
      for (int dc = 0; dc < 4; dc++)
        *(float4*)(qb + dc * 60) = make_float4(acc[0][dc], acc[1][dc], acc[2][dc], acc[3][dc]);
    }
  }
}

// ---------------------------------------------------------------------------
// K2b: attention per (b,h), 256 threads (round-11 structure — best measured).
// relT staged via coalesced relTg float4s (only change vs round 11).
// ---------------------------------------------------------------------------
__global__ __launch_bounds__(256) void k_attn(
    const float* __restrict__ qkvo, const int* __restrict__ loc_seq,
    const float* __restrict__ relTg,   // layer slice [10][120]
    float* __restrict__ o) {
  int bh = blockIdx.x;
  int b = bh >> 3, h = bh & 7;
  int tid = threadIdx.x;

  __shared__ __align__(16) float qs[HDD * 60];
  __shared__ __align__(16) float ks[HDD * 60];
  __shared__ __align__(16) float vs[HDD * 60];
  __shared__ __align__(16) float relT[HDD * 120];
  __shared__ __align__(16) float sc[60 * SCS];
  __shared__ __align__(16) float rsum[64];
  __shared__ float msk[60];

  const float4* src = (const float4*)(qkvo + (size_t)b * 14400);
  float4* q4 = (float4*)qs; float4* k4 = (float4*)ks; float4* v4 = (float4*)vs;
  for (int i = tid; i < 150; i += 256) {
    q4[i] = src[h * 150 + i];
    k4[i] = src[1200 + h * 150 + i];
    v4[i] = src[2400 + h * 150 + i];
  }
  const float4* rg4 = (const float4*)relTg;
  float4* relT4 = (float4*)relT;
  for (int i = tid; i < 300; i += 256) relT4[i] = rg4[i];
  if (tid < 60) msk[tid] = (loc_seq[b * LL + tid] == 0) ? 1.0f : 0.0f;
  __syncthreads();

  if (tid < 225) {
    int ig = tid / 15, jg = tid % 15;
    int i0 = ig * 4, j0 = jg * 4;
    int w0 = j0 - i0 + 56;
    float acc[4][4] = {};
    #pragma unroll
    for (int d = 0; d < 10; d++) {
      float4 qv = *(const float4*)(qs + d * 60 + i0);
      float4 kv = *(const float4*)(ks + d * 60 + j0);
      float4 rA = *(const float4*)(relT + d * 120 + w0);
      float4 rB = *(const float4*)(relT + d * 120 + w0 + 4);
      float rr[8] = {rA.x, rA.y, rA.z, rA.w, rB.x, rB.y, rB.z, rB.w};
      const float* qp = (const float*)&qv;
      const float* kp = (const float*)&kv;
      #pragma unroll
      for (int di = 0; di < 4; di++)
        #pragma unroll
        for (int dj = 0; dj < 4; dj++)
          acc[di][dj] += qp[di] * (kp[dj] + rr[dj - di + 3]);
    }
    const float scale = 0.31622776601683794f;
    #pragma unroll
    for (int di = 0; di < 4; di++) {
      #pragma unroll
      for (int dj = 0; dj < 4; dj++) {
        float v = acc[di][dj] * scale;
        if (msk[j0 + dj] != 0.0f) v = -1e30f;
        acc[di][dj] = v;
      }
      *(float4*)(sc + (i0 + di) * SCS + j0) =
          make_float4(acc[di][0], acc[di][1], acc[di][2], acc[di][3]);
    }
  }
  __syncthreads();

  if (tid < 60) {
    float* row = sc + tid * SCS;
    int c = (tid >> 3) & 7;
    float m0 = -3.0e38f, m1 = -3.0e38f, m2 = -3.0e38f, m3 = -3.0e38f;
    #pragma unroll
    for (int s = 0; s < 15; s++) {
      int k = c + s; if (k >= 15) k -= 15;
      float4 v = *(const float4*)(row + 4 * k);
      m0 = fmaxf(m0, v.x); m1 = fmaxf(m1, v.y);
      m2 = fmaxf(m2, v.z); m3 = fmaxf(m3, v.w);
    }
    float m = fmaxf(fmaxf(m0, m1), fmaxf(m2, m3));
    float s0 = 0.0f, s1 = 0.0f, s2 = 0.0f, s3 = 0.0f;
    #pragma unroll
    for (int s = 0; s < 15; s++) {
      int k = c + s; if (k >= 15) k -= 15;
      float4 v = *(float4*)(row + 4 * k);
      v.x = __expf(v.x - m); v.y = __expf(v.y - m);
      v.z = __expf(v.z - m); v.w = __expf(v.w - m);
      *(float4*)(row + 4 * k) = v;
      s0 += v.x; s1 += v.y; s2 += v.z; s3 += v.w;
    }
    rsum[tid] = 1.0f / (s0 + s1 + s2 + s3);
  }
  __syncthreads();

  if (tid < 150) {
    int ig = tid / 10, d = tid % 10;
    float acc[4] = {0, 0, 0, 0};
    #pragma unroll 5
    for (int jq = 0; jq < 15; jq++) {
      float4 vv = *(const float4*)(vs + d * 60 + jq * 4);
      #pragma unroll
      for (int di = 0; di < 4; di++) {
        float4 av = *(const float4*)(sc + (ig + 15 * di) * SCS + jq * 4);
        acc[di] += av.x * vv.x + av.y * vv.y + av.z * vv.z + av.w * vv.w;
      }
    }
    #pragma unroll
    for (int di = 0; di < 4; di++) {
      float r = rsum[ig + 15 * di];
      o[((size_t)b * 60 + ig + 15 * di) * 80 + h * 10 + d] = acc[di] * r;
    }
  }
}

// ---------------------------------------------------------------------------
// K3: x = LN(x + o @ proj_w + proj_b)  — 48 tokens/block
// ---------------------------------------------------------------------------
__global__ __launch_bounds__(256) void k_proj_ln(
    const float* __restrict__ o, const float* __restrict__ proj_w,
    const float* __restrict__ proj_b, const float* __restrict__ g,
    const float* __restrict__ be, float* __restrict__ x) {
  int tok0 = blockIdx.x * 48, tid = threadIdx.x;
  __shared__ __align__(16) float os[48 * XP * 4];
  __shared__ __align__(16) float ws[80 * 80];
  __shared__ float mstd[96];

  float4* os4 = (float4*)os;
  const float4* ob4 = (const float4*)(o + (size_t)tok0 * 80);
  for (int i = tid; i < 960; i += 256) os4[(i / 20) * XP + (i % 20)] = ob4[i];
  float4* ws4 = (float4*)ws;
  for (int i = tid; i < 1600; i += 256)
    ws4[i] = *(const float4*)(proj_w + (i / 20) * 80 + (i % 20) * 4);
  __syncthreads();

  int tg = tid / 20, cg = tid % 20, t0 = tg * 4;
  float acc[4][4] = {};
  if (tid < 240) {
    #pragma unroll
    for (int iq = 0; iq < 20; iq++) {
      float4 xv[4], wv[4];
      #pragma unroll
      for (int dt = 0; dt < 4; dt++) xv[dt] = os4[(t0 + dt) * XP + iq];
      #pragma unroll
      for (int di = 0; di < 4; di++) wv[di] = ws4[(iq * 4 + di) * 20 + cg];
      #pragma unroll
      for (int dt = 0; dt < 4; dt++) {
        const float* xp = (const float*)&xv[dt];
        #pragma unroll
        for (int di = 0; di < 4; di++) {
          const float* wp = (const float*)&wv[di];
          #pragma unroll
          for (int dc = 0; dc < 4; dc++) acc[dt][dc] += xp[di] * wp[dc];
        }
      }
    }
  }
  __syncthreads();
  if (tid < 240) {
    float4 pb = *(const float4*)(proj_b + cg * 4);
    const float* pbp = (const float*)&pb;
    #pragma unroll
    for (int dt = 0; dt < 4; dt++) {
      float4 xr = *(const float4*)(x + (size_t)(tok0 + t0 + dt) * 80 + cg * 4);
      const float* xrp = (const float*)&xr;
      float4 out;
      out.x = acc[dt][0] + pbp[0] + xrp[0];
      out.y = acc[dt][1] + pbp[1] + xrp[1];
      out.z = acc[dt][2] + pbp[2] + xrp[2];
      out.w = acc[dt][3] + pbp[3] + xrp[3];
      os4[(t0 + dt) * XP + cg] = out;
    }
  }
  __syncthreads();
  if (tid < 48) {
    float s = 0.0f, s2 = 0.0f;
    #pragma unroll
    for (int iq = 0; iq < 20; iq++) {
      float4 v = os4[tid * XP + iq];
      s  += v.x + v.y + v.z + v.w;
      s2 += v.x * v.x + v.y * v.y + v.z * v.z + v.w * v.w;
    }
    float mean = s / 80.0f;
    float var  = fmaxf(s2 / 80.0f - mean * mean, 0.0f);
    mstd[tid] = mean; mstd[48 + tid] = rsqrtf(var + 1e-5f);
  }
  __syncthreads();
  for (int e = tid; e < 960; e += 256) {
    int t = e / 20, c4 = e % 20;
    float4 v = os4[t * XP + c4];
    float4 gg = *(const float4*)(g + c4 * 4);
    float4 bb = *(const float4*)(be + c4 * 4);
    float m = mstd[t], r = mstd[48 + t];
    float4 out;
    out.x = (v.x - m) * r * gg.x + bb.x;
    out.y = (v.y - m) * r * gg.y + bb.y;
    out.z = (v.z - m) * r * gg.z + bb.z;
    out.w = (v.w - m) * r * gg.w + bb.w;
    ((float4*)(x + (size_t)tok0 * 80))[e] = out;
  }
}

// ---------------------------------------------------------------------------
// K4: fused FFN: x = LN(x + W2ᵀgelu(W1ᵀx + b1) + b2)  — 48 tokens/block
// ---------------------------------------------------------------------------
__global__ __launch_bounds__(256) void k_ffn(
    const float* __restrict__ w1, const float* __restrict__ b1,
    const float* __restrict__ w2, const float* __restrict__ b2,
    const float* __restrict__ g, const float* __restrict__ be,
    float* __restrict__ x) {
  int tok0 = blockIdx.x * 48, tid = threadIdx.x;
  __shared__ __align__(16) float xs[48 * XP * 4];
  __shared__ __align__(16) float hs[48 * HP * 4];
  __shared__ __align__(16) float ws[80 * 80];
  __shared__ float mstd[96];

  float4* xs4 = (float4*)xs;
  float4* hs4 = (float4*)hs;
  float4* ws4 = (float4*)ws;
  const float4* xb4 = (const float4*)(x + (size_t)tok0 * 80);
  for (int i = tid; i < 960; i += 256) xs4[(i / 20) * XP + (i % 20)] = xb4[i];

  int tg = tid / 20, cg = tid % 20, t0 = tg * 4;

  for (int c0 = 0; c0 < 160; c0 += 80) {
    __syncthreads();
    for (int i = tid; i < 1600; i += 256)
      ws4[i] = *(const float4*)(w1 + (i / 20) * 160 + c0 + (i % 20) * 4);
    __syncthreads();
    if (tid < 240) {
      float acc[4][4] = {};
      #pragma unroll
      for (int iq = 0; iq < 20; iq++) {
        float4 xv[4], wv[4];
        #pragma unroll
        for (int dt = 0; dt < 4; dt++) xv[dt] = xs4[(t0 + dt) * XP + iq];
        #pragma unroll
        for (int di = 0; di < 4; di++) wv[di] = ws4[(iq * 4 + di) * 20 + cg];
        #pragma unroll
        for (int dt = 0; dt < 4; dt++) {
          const float* xp = (const float*)&xv[dt];
          #pragma unroll
          for (int di = 0; di < 4; di++) {
            const float* wp = (const float*)&wv[di];
            #pragma unroll
            for (int dc = 0; dc < 4; dc++) acc[dt][dc] += xp[di] * wp[dc];
          }
        }
      }
      float4 bb = *(const float4*)(b1 + c0 + cg * 4);
      const float* bp = (const float*)&bb;
      #pragma unroll
      for (int dt = 0; dt < 4; dt++) {
        float4 out;
        float* op = (float*)&out;
        #pragma unroll
        for (int dc = 0; dc < 4; dc++)
          op[dc] = gelu_f(acc[dt][dc] + bp[dc]);
        hs4[(t0 + dt) * HP + c0 / 4 + cg] = out;
      }
    }
  }

  float acc[4][4] = {};
  for (int k0 = 0; k0 < 160; k0 += 80) {
    __syncthreads();
    for (int i = tid; i < 1600; i += 256)
      ws4[i] = *(const float4*)(w2 + (size_t)(k0 + i / 20) * 80 + (i % 20) * 4);
    __syncthreads();
    if (tid < 240) {
      #pragma unroll
      for (int iq = 0; iq < 20; iq++) {
        float4 hv[4], wv[4];
        #pragma unroll
        for (int dt = 0; dt < 4; dt++) hv[dt] = hs4[(t0 + dt) * HP + k0 / 4 + iq];
        #pragma unroll
        for (int di = 0; di < 4; di++) wv[di] = ws4[(iq * 4 + di) * 20 + cg];
        #pragma unroll
        for (int dt = 0; dt < 4; dt++) {
          const float* hp = (const float*)&hv[dt];
          #pragma unroll
          for (int di = 0; di < 4; di++) {
            const float* wp = (const float*)&wv[di];
            #pragma unroll
            for (int dc = 0; dc < 4; dc++) acc[dt][dc] += hp[di] * wp[dc];
          }
        }
      }
    }
  }
  __syncthreads();
  if (tid < 240) {
    float4 bb = *(const float4*)(b2 + cg * 4);
    const float* bp = (const float*)&bb;
    #pragma unroll
    for (int dt = 0; dt < 4; dt++) {
      float4 xr = xs4[(t0 + dt) * XP + cg];
      const float* xrp = (const float*)&xr;
      float4 out;
      out.x = acc[dt][0] + bp[0] + xrp[0];
      out.y = acc[dt][1] + bp[1] + xrp[1];
      out.z = acc[dt][2] + bp[2] + xrp[2];
      out.w = acc[dt][3] + bp[3] + xrp[3];
      hs4[(t0 + dt) * HP + cg] = out;
    }
  }
  __syncthreads();
  if (tid < 48) {
    float s = 0.0f, s2 = 0.0f;
    #pragma unroll
    for (int iq = 0; iq < 20; iq++) {
      float4 v = hs4[tid * HP + iq];
      s  += v.x + v.y + v.z + v.w;
      s2 += v.x * v.x + v.y * v.y + v.z * v.z + v.w * v.w;
    }
    float mean = s / 80.0f;
    float var  = fmaxf(s2 / 80.0f - mean * mean, 0.0f);
    mstd[tid] = mean; mstd[48 + tid] = rsqrtf(var + 1e-5f);
  }
  __syncthreads();
  for (int e = tid; e < 960; e += 256) {
    int t = e / 20, c4 = e % 20;
    float4 v = hs4[t * HP + c4];
    float4 gg = *(const float4*)(g + c4 * 4);
    float4 bb = *(const float4*)(be + c4 * 4);
    float m = mstd[t], r = mstd[48 + t];
    float4 out;
    out.x = (v.x - m) * r * gg.x + bb.x;
    out.y = (v.y - m) * r * gg.y + bb.y;
    out.z = (v.z - m) * r * gg.z + bb.z;
    out.w = (v.w - m) * r * gg.w + bb.w;
    ((float4*)(x + (size_t)tok0 * 80))[e] = out;
  }
}

// ---------------------------------------------------------------------------
// K5: final LN at gathered position + fnorm + h1 = gelu(final@pr_w1+pr_b1)
// ---------------------------------------------------------------------------
__global__ __launch_bounds__(128) void k_final(
    const float* __restrict__ x, const int* __restrict__ seq_len,
    const float* __restrict__ fn_g, const float* __restrict__ fn_b,
    const float* __restrict__ pr_w1, const float* __restrict__ pr_b1,
    float* __restrict__ fnorm, float* __restrict__ h1) {
  int b = blockIdx.x, tid = threadIdx.x;
  __shared__ float red[128], red2[128];
  __shared__ float fbuf[DD];
  int t = seq_len[b] - 1; t = min(max(t, 0), LL - 1);
  float v = 0.0f;
  if (tid < DD) v = x[((size_t)b * LL + t) * DD + tid];
  red[tid]  = (tid < DD) ? v : 0.0f;
  red2[tid] = (tid < DD) ? v * v : 0.0f;
  __syncthreads();
  for (int s = 64; s > 0; s >>= 1) {
    if (tid < s) { red[tid] += red[tid + s]; red2[tid] += red2[tid + s]; }
    __syncthreads();
  }
  float mean = red[0] / DD;
  float var  = fmaxf(red2[0] / DD - mean * mean, 0.0f);
  float rstd = rsqrtf(var + 1e-5f);
  float f = 0.0f;
  if (tid < DD) { f = (v - mean) * rstd * fn_g[tid] + fn_b[tid]; fbuf[tid] = f; }
  __syncthreads();
  red[tid] = (tid < DD) ? f * f : 0.0f;
  __syncthreads();
  for (int s = 64; s > 0; s >>= 1) {
    if (tid < s) red[tid] += red[tid + s];
    __syncthreads();
  }
  float rn = 1.0f / fmaxf(sqrtf(red[0]), 1e-12f);
  if (tid < DD) {
    fnorm[(size_t)b * DD + tid] = f * rn;
    float gacc = pr_b1[tid];
    for (int i = 0; i < DD; i++) gacc += fbuf[i] * pr_w1[i * DD + tid];
    h1[(size_t)b * DD + tid] = gelu_f(gacc);
  }
}

// ---------------------------------------------------------------------------
// K6: normalize proto rows -> transposed pnormT[k][c]
// ---------------------------------------------------------------------------
__global__ __launch_bounds__(128) void k_pnorm(
    const float* __restrict__ protos, float* __restrict__ pnormT) {
  int c = blockIdx.x, tid = threadIdx.x;
  __shared__ float red[128];
  float v = 0.0f;
  if (tid < DD) v = protos[(size_t)c * DD + tid];
  red[tid] = (tid < DD) ? v * v : 0.0f;
  __syncthreads();
  for (int s = 64; s > 0; s >>= 1) {
    if (tid < s) red[tid] += red[tid + s];
    __syncthreads();
  }
  float rn = 1.0f / fmaxf(sqrtf(red[0]), 1e-12f);
  if (tid < DD) pnormT[(size_t)tid * NLOC + c] = v * rn;
}

// ---------------------------------------------------------------------------
// K7: logits — 4 batch rows per block
// ---------------------------------------------------------------------------
__global__ __launch_bounds__(256) void k_logits(
    const float* __restrict__ h1, const float* __restrict__ fnorm,
    const float* __restrict__ pr_w2, const float* __restrict__ pr_b2,
    const float* __restrict__ pnormT, const float* __restrict__ temp,
    float* __restrict__ out) {
  int b0 = (blockIdx.x / 5) * 4, cb = blockIdx.x % 5;
  int tid = threadIdx.x;
  int c = cb * 256 + tid;
  __shared__ float h1s[4][DD], fns[4][DD];
  for (int i = tid; i < 4 * DD; i += 256) {
    int j = i / DD, k = i % DD;
    h1s[j][k] = h1[(size_t)(b0 + j) * DD + k];
    fns[j][k] = fnorm[(size_t)(b0 + j) * DD + k];
  }
  __syncthreads();
  if (c < NLOC) {
    float a1[4] = {0, 0, 0, 0}, a2[4] = {0, 0, 0, 0};
    for (int k = 0; k < DD; k++) {
      float w = pr_w2[(size_t)k * NLOC + c];
      float p = pnormT[(size_t)k * NLOC + c];
      #pragma unroll
      for (int j = 0; j < 4; j++) {
        a1[j] += h1s[j][k] * w;
        a2[j] += fns[j][k] * p;
      }
    }
    float pb = pr_b2[c];
    float tt = fminf(fmaxf(temp[0], 0.5f), 3.0f);
    #pragma unroll
    for (int j = 0; j < 4; j++)
      out[(size_t)(b0 + j) * NLOC + c] = (0.5f * (a1[j] + pb) + 7.5f * a2[j]) / tt;
  }
}

// ---------------------------------------------------------------------------
extern "C" void kernel_launch(void* const* d_in, const int* in_sizes, int n_in,
                              void* d_out, int out_size, void* d_ws, size_t ws_size,
                              hipStream_t stream) {
  const int* loc_seq   = (const int*)d_in[0];
  const int* user_seq  = (const int*)d_in[1];
  const int* wk_seq    = (const int*)d_in[2];
  const int* sm_seq    = (const int*)d_in[3];
  const int* dur_seq   = (const int*)d_in[4];
  const int* diff_seq  = (const int*)d_in[5];
  const int* seq_len   = (const int*)d_in[6];
  const float* loc_table = (const float*)d_in[7];
  const float* user_table= (const float*)d_in[8];
  const float* wk_table  = (const float*)d_in[9];
  const float* hr_table  = (const float*)d_in[10];
  const float* in_w   = (const float*)d_in[11];
  const float* in_b   = (const float*)d_in[12];
  const float* in_g   = (const float*)d_in[13];
  const float* in_be  = (const float*)d_in[14];
  const float* pos_emb= (const float*)d_in[15];
  const float* qkv_w  = (const float*)d_in[16];
  const float* proj_w = (const float*)d_in[17];
  const float* proj_b = (const float*)d_in[18];
  const float* rel_emb= (const float*)d_in[19];
  const float* n1_g   = (const float*)d_in[20];
  const float* n1_b   = (const float*)d_in[21];
  const float* ffn_w1 = (const float*)d_in[22];
  const float* ffn_b1 = (const float*)d_in[23];
  const float* ffn_w2 = (const float*)d_in[24];
  const float* ffn_b2 = (const float*)d_in[25];
  const float* n2_g   = (const float*)d_in[26];
  const float* n2_b   = (const float*)d_in[27];
  const float* fn_g   = (const float*)d_in[28];
  const float* fn_b   = (const float*)d_in[29];
  const float* pr_w1  = (const float*)d_in[30];
  const float* pr_b1  = (const float*)d_in[31];
  const float* pr_w2  = (const float*)d_in[32];
  const float* pr_b2  = (const float*)d_in[33];
  const float* protos = (const float*)d_in[34];
  const float* temp   = (const float*)d_in[35];
  float* out = (float*)d_out;

  float* x      = (float*)d_ws;
  float* o      = x + (size_t)BB * LL * DD;
  float* qkvo   = o + (size_t)BB * LL * DD;
  float* fnorm  = qkvo + (size_t)BB * 14400;
  float* h1     = fnorm + (size_t)BB * DD;
  float* pnormT = h1 + (size_t)BB * DD;
  float* relTg  = pnormT + (size_t)DD * NLOC;   // 3600 floats

  k_rprep<<<15, 256, 0, stream>>>(rel_emb, relTg);

  k_embed<<<BB * LL / 48, 256, 0, stream>>>(loc_seq, user_seq, wk_seq, sm_seq,
                                            dur_seq, diff_seq, loc_table,
                                            user_table, wk_table, hr_table,
                                            in_w, in_b, in_g, in_be, pos_emb, x);

  for (int l = 0; l < NLNUM; l++) {
    k_qkv<<<BB, 256, 0, stream>>>(x, qkv_w + (size_t)l * 80 * 240, qkvo);
    k_attn<<<BB * HH, 256, 0, stream>>>(qkvo, loc_seq,
                                        relTg + (size_t)l * 1200, o);
    k_proj_ln<<<BB * LL / 48, 256, 0, stream>>>(o, proj_w + (size_t)l * DD * DD,
                                                proj_b + (size_t)l * DD,
                                                n1_g + (size_t)l * DD,
                                                n1_b + (size_t)l * DD, x);
    k_ffn<<<BB * LL / 48, 256, 0, stream>>>(ffn_w1 + (size_t)l * DD * DFF,
                                            ffn_b1 + (size_t)l * DFF,
                                            ffn_w2 + (size_t)l * DFF * DD,
                                            ffn_b2 + (size_t)l * DD,
                                            n2_g + (size_t)l * DD,
                                            n2_b + (size_t)l * DD, x);
  }

  k_pnorm<<<NLOC, 128, 0, stream>>>(protos, pnormT);
  k_final<<<BB, 128, 0, stream>>>(x, seq_len, fn_g, fn_b, pr_w1, pr_b1, fnorm, h1);
  k_logits<<<(BB / 4) * 5, 256, 0, stream>>>(h1, fnorm, pr_w2, pr_b2, pnormT, temp, out);
}

// Round 14
// 1616.566 us; speedup vs baseline: 1.0723x; 1.0140x over previous
//
#include <hip/hip_runtime.h>
#include <hip/hip_bf16.h>
#include <math.h>

#define BB   2048
#define LL   60
#define DD   80
#define HH   8
#define HDD  10
#define NLNUM 3
#define NLOC 1187
#define DFF  160
#define IN_DIM 138
#define RELN 119
#define SCS  68   // sc row stride (floats): 68 mod 32 = 4 -> rows spread banks
#define XP   21   // padded tile row stride in float4 (84 words, !=0 mod 32)
#define HP   41   // padded h-tile row stride in float4 (164 words)
#define VP   35   // vin row stride in float4 (140 words)

// Branchless gelu: erf via Abramowitz-Stegun 7.1.26 (|err| <= 1.5e-7).
__device__ __forceinline__ float gelu_f(float a) {
  float x = fabsf(a) * 0.70710678118654752f;
  float t = 1.0f / (1.0f + 0.3275911f * x);
  float y = t * (0.254829592f + t * (-0.284496736f + t * (1.421413741f +
            t * (-1.453152027f + t * 1.061405429f))));
  float e = 1.0f - y * __expf(-x * x);           // erf(|x|)
  float erf_s = copysignf(e, a);
  return 0.5f * a * (1.0f + erf_s);
}

// ---------------------------------------------------------------------------
// K0: pre-transpose rel_emb [l][p:119][d:10] -> relTg [l][d:10][p:120]
// ---------------------------------------------------------------------------
__global__ __launch_bounds__(256) void k_rprep(
    const float* __restrict__ rel_emb, float* __restrict__ relTg) {
  int idx = blockIdx.x * 256 + threadIdx.x;   // 3*10*120 = 3600
  if (idx >= 3600) return;
  int p = idx % 120;
  int d = (idx / 120) % 10;
  int l = idx / 1200;
  float v = 0.0f;
  if (p < RELN) v = rel_emb[l * RELN * HDD + p * HDD + d];
  relTg[idx] = v;
}

// ---------------------------------------------------------------------------
// K1: embed+inproj+LN as a 48-token GEMM block
// ---------------------------------------------------------------------------
__global__ __launch_bounds__(256) void k_embed(
    const int* __restrict__ loc_seq, const int* __restrict__ user_seq,
    const int* __restrict__ wk_seq, const int* __restrict__ sm_seq,
    const int* __restrict__ dur_seq, const int* __restrict__ diff_seq,
    const float* __restrict__ loc_table, const float* __restrict__ user_table,
    const float* __restrict__ wk_table, const float* __restrict__ hr_table,
    const float* __restrict__ in_w, const float* __restrict__ in_b,
    const float* __restrict__ in_g, const float* __restrict__ in_be,
    const float* __restrict__ pos_emb, float* __restrict__ x) {
  int tok0 = blockIdx.x * 48, tid = threadIdx.x;
  __shared__ __align__(16) float vin[48 * VP * 4];
  __shared__ __align__(16) float ws[140 * 80];
  __shared__ float mstd[96];

  float4* vin4 = (float4*)vin;
  float4* ws4  = (float4*)ws;

  for (int i = tid; i < 140 * 20; i += 256) {
    int r = i / 20, c = i % 20;
    float4 v = make_float4(0.0f, 0.0f, 0.0f, 0.0f);
    if (r < IN_DIM) v = *(const float4*)(in_w + r * 80 + c * 4);
    ws4[i] = v;
  }
  for (int i = tid; i < 48 * 35; i += 256) {
    int t = i / 35, s = i % 35;
    int tok = tok0 + t;
    float4 v;
    if (s < 20) {
      int loc = loc_seq[tok];
      v = *(const float4*)(loc_table + (size_t)loc * 80 + s * 4);
    } else if (s < 26) {
      int usr = user_seq[(tok / LL) * LL];
      v = *(const float4*)(user_table + usr * 24 + (s - 20) * 4);
    } else if (s < 30) {
      int wk = wk_seq[tok];
      v = *(const float4*)(wk_table + wk * 16 + (s - 26) * 4);
    } else if (s < 34) {
      int hr = sm_seq[tok] / 60; hr = min(max(hr, 0), 23);
      v = *(const float4*)(hr_table + hr * 16 + (s - 30) * 4);
    } else {
      v.x = (float)diff_seq[tok] / 10.0f;
      v.y = (float)dur_seq[tok] / 300.0f;
      v.z = 0.0f; v.w = 0.0f;
    }
    vin4[t * VP + s] = v;
  }
  __syncthreads();

  int tg = tid / 20, cg = tid % 20, t0 = tg * 4;
  float acc[4][4] = {};
  if (tid < 240) {
    #pragma unroll 7
    for (int iq = 0; iq < 35; iq++) {
      float4 xv[4], wv[4];
      #pragma unroll
      for (int dt = 0; dt < 4; dt++) xv[dt] = vin4[(t0 + dt) * VP + iq];
      #pragma unroll
      for (int di = 0; di < 4; di++) wv[di] = ws4[(iq * 4 + di) * 20 + cg];
      #pragma unroll
      for (int dt = 0; dt < 4; dt++) {
        const float* xp = (const float*)&xv[dt];
        #pragma unroll
        for (int di = 0; di < 4; di++) {
          const float* wp = (const float*)&wv[di];
          #pragma unroll
          for (int dc = 0; dc < 4; dc++) acc[dt][dc] += xp[di] * wp[dc];
        }
      }
    }
  }
  __syncthreads();
  if (tid < 240) {
    float4 bb = *(const float4*)(in_b + cg * 4);
    const float* bp = (const float*)&bb;
    #pragma unroll
    for (int dt = 0; dt < 4; dt++) {
      float4 y;
      y.x = acc[dt][0] + bp[0];
      y.y = acc[dt][1] + bp[1];
      y.z = acc[dt][2] + bp[2];
      y.w = acc[dt][3] + bp[3];
      vin4[(t0 + dt) * VP + cg] = y;
    }
  }
  __syncthreads();
  if (tid < 48) {
    float s = 0.0f, s2 = 0.0f;
    #pragma unroll
    for (int iq = 0; iq < 20; iq++) {
      float4 v = vin4[tid * VP + iq];
      s  += v.x + v.y + v.z + v.w;
      s2 += v.x * v.x + v.y * v.y + v.z * v.z + v.w * v.w;
    }
    float mean = s / 80.0f;
    float var  = fmaxf(s2 / 80.0f - mean * mean, 0.0f);
    mstd[tid] = mean; mstd[48 + tid] = rsqrtf(var + 1e-5f);
  }
  __syncthreads();
  for (int e = tid; e < 960; e += 256) {
    int t = e / 20, c4 = e % 20;
    float4 v = vin4[t * VP + c4];
    float4 gg = *(const float4*)(in_g + c4 * 4);
    float4 bb = *(const float4*)(in_be + c4 * 4);
    float4 pe = *(const float4*)(pos_emb + ((tok0 + t) % LL) * 80 + c4 * 4);
    float m = mstd[t], r = mstd[48 + t];
    float4 out;
    out.x = (v.x - m) * r * gg.x + bb.x + pe.x;
    out.y = (v.y - m) * r * gg.y + bb.y + pe.y;
    out.z = (v.z - m) * r * gg.z + bb.z + pe.z;
    out.w = (v.w - m) * r * gg.w + bb.w + pe.w;
    ((float4*)(x + (size_t)tok0 * 80))[e] = out;
  }
}

// ---------------------------------------------------------------------------
// K2a: qkv GEMM per batch row b: [60 x 80] @ [80 x 240] -> qkvo[b][c][t]
// ---------------------------------------------------------------------------
__global__ __launch_bounds__(256) void k_qkv(
    const float* __restrict__ x, const float* __restrict__ qkv_w,
    float* __restrict__ qkvo) {
  int b = blockIdx.x, tid = threadIdx.x;
  __shared__ __align__(16) float xs[LL * XP * 4];
  __shared__ __align__(16) float ws[DD * DD];

  const float4* xb4 = (const float4*)(x + (size_t)b * LL * DD);
  float4* xs4 = (float4*)xs;
  for (int i = tid; i < LL * 20; i += 256) xs4[(i / 20) * XP + (i % 20)] = xb4[i];
  float4* ws4 = (float4*)ws;

  for (int c0 = 0; c0 < 240; c0 += 80) {
    __syncthreads();
    for (int i = tid; i < 80 * 20; i += 256)
      ws4[i] = *(const float4*)(qkv_w + (i / 20) * 240 + c0 + (i % 20) * 4);
    __syncthreads();
    for (int slot = tid; slot < 300; slot += 256) {
      int tg = slot / 20, cg = slot % 20;
      int t0 = tg * 4;
      float acc[4][4] = {};
      #pragma unroll
      for (int iq = 0; iq < 20; iq++) {
        float4 xv[4], wv[4];
        #pragma unroll
        for (int dt = 0; dt < 4; dt++) xv[dt] = xs4[(t0 + dt) * XP + iq];
        #pragma unroll
        for (int di = 0; di < 4; di++) wv[di] = ws4[(iq * 4 + di) * 20 + cg];
        #pragma unroll
        for (int dt = 0; dt < 4; dt++) {
          const float* xp = (const float*)&xv[dt];
          #pragma unroll
          for (int di = 0; di < 4; di++) {
            const float* wp = (const float*)&wv[di];
            #pragma unroll
            for (int dc = 0; dc < 4; dc++) acc[dt][dc] += xp[di] * wp[dc];
          }
        }
      }
      float* qb = qkvo + (size_t)b * 14400 + (size_t)(c0 + cg * 4) * 60 + t0;
      #pragma unroll
      for (int dc = 0; dc < 4; dc++)
        *(float4*)(qb + dc * 60) = make_float4(acc[0][dc], acc[1][dc], acc[2][dc], acc[3][dc]);
    }
  }
}

// ---------------------------------------------------------------------------
// K2b: attention per (b,h), 256 threads; relT staged via coalesced relTg.
// ---------------------------------------------------------------------------
__global__ __launch_bounds__(256) void k_attn(
    const float* __restrict__ qkvo, const int* __restrict__ loc_seq,
    const float* __restrict__ relTg,   // layer slice [10][120]
    float* __restrict__ o) {
  int bh = blockIdx.x;
  int b = bh >> 3, h = bh & 7;
  int tid = threadIdx.x;

  __shared__ __align__(16) float qs[HDD * 60];
  __shared__ __align__(16) float ks[HDD * 60];
  __shared__ __align__(16) float vs[HDD * 60];
  __shared__ __align__(16) float relT[HDD * 120];
  __shared__ __align__(16) float sc[60 * SCS];
  __shared__ __align__(16) float rsum[64];
  __shared__ float msk[60];

  const float4* src = (const float4*)(qkvo + (size_t)b * 14400);
  float4* q4 = (float4*)qs; float4* k4 = (float4*)ks; float4* v4 = (float4*)vs;
  for (int i = tid; i < 150; i += 256) {
    q4[i] = src[h * 150 + i];
    k4[i] = src[1200 + h * 150 + i];
    v4[i] = src[2400 + h * 150 + i];
  }
  const float4* rg4 = (const float4*)relTg;
  float4* relT4 = (float4*)relT;
  for (int i = tid; i < 300; i += 256) relT4[i] = rg4[i];
  if (tid < 60) msk[tid] = (loc_seq[b * LL + tid] == 0) ? 1.0f : 0.0f;
  __syncthreads();

  if (tid < 225) {
    int ig = tid / 15, jg = tid % 15;
    int i0 = ig * 4, j0 = jg * 4;
    int w0 = j0 - i0 + 56;
    float acc[4][4] = {};
    #pragma unroll
    for (int d = 0; d < 10; d++) {
      float4 qv = *(const float4*)(qs + d * 60 + i0);
      float4 kv = *(const float4*)(ks + d * 60 + j0);
      float4 rA = *(const float4*)(relT + d * 120 + w0);
      float4 rB = *(const float4*)(relT + d * 120 + w0 + 4);
      float rr[8] = {rA.x, rA.y, rA.z, rA.w, rB.x, rB.y, rB.z, rB.w};
      const float* qp = (const float*)&qv;
      const float* kp = (const float*)&kv;
      #pragma unroll
      for (int di = 0; di < 4; di++)
        #pragma unroll
        for (int dj = 0; dj < 4; dj++)
          acc[di][dj] += qp[di] * (kp[dj] + rr[dj - di + 3]);
    }
    const float scale = 0.31622776601683794f;
    #pragma unroll
    for (int di = 0; di < 4; di++) {
      #pragma unroll
      for (int dj = 0; dj < 4; dj++) {
        float v = acc[di][dj] * scale;
        if (msk[j0 + dj] != 0.0f) v = -1e30f;
        acc[di][dj] = v;
      }
      *(float4*)(sc + (i0 + di) * SCS + j0) =
          make_float4(acc[di][0], acc[di][1], acc[di][2], acc[di][3]);
    }
  }
  __syncthreads();

  if (tid < 60) {
    float* row = sc + tid * SCS;
    int c = (tid >> 3) & 7;
    float m0 = -3.0e38f, m1 = -3.0e38f, m2 = -3.0e38f, m3 = -3.0e38f;
    #pragma unroll
    for (int s = 0; s < 15; s++) {
      int k = c + s; if (k >= 15) k -= 15;
      float4 v = *(const float4*)(row + 4 * k);
      m0 = fmaxf(m0, v.x); m1 = fmaxf(m1, v.y);
      m2 = fmaxf(m2, v.z); m3 = fmaxf(m3, v.w);
    }
    float m = fmaxf(fmaxf(m0, m1), fmaxf(m2, m3));
    float s0 = 0.0f, s1 = 0.0f, s2 = 0.0f, s3 = 0.0f;
    #pragma unroll
    for (int s = 0; s < 15; s++) {
      int k = c + s; if (k >= 15) k -= 15;
      float4 v = *(float4*)(row + 4 * k);
      v.x = __expf(v.x - m); v.y = __expf(v.y - m);
      v.z = __expf(v.z - m); v.w = __expf(v.w - m);
      *(float4*)(row + 4 * k) = v;
      s0 += v.x; s1 += v.y; s2 += v.z; s3 += v.w;
    }
    rsum[tid] = 1.0f / (s0 + s1 + s2 + s3);
  }
  __syncthreads();

  if (tid < 150) {
    int ig = tid / 10, d = tid % 10;
    float acc[4] = {0, 0, 0, 0};
    #pragma unroll 5
    for (int jq = 0; jq < 15; jq++) {
      float4 vv = *(const float4*)(vs + d * 60 + jq * 4);
      #pragma unroll
      for (int di = 0; di < 4; di++) {
        float4 av = *(const float4*)(sc + (ig + 15 * di) * SCS + jq * 4);
        acc[di] += av.x * vv.x + av.y * vv.y + av.z * vv.z + av.w * vv.w;
      }
    }
    #pragma unroll
    for (int di = 0; di < 4; di++) {
      float r = rsum[ig + 15 * di];
      o[((size_t)b * 60 + ig + 15 * di) * 80 + h * 10 + d] = acc[di] * r;
    }
  }
}

// ---------------------------------------------------------------------------
// K3: fused proj+LN1+FFN+LN2 — 48 tokens/block.
// Eliminates the x round-trip between k_proj_ln and k_ffn (78 MB/layer)
// plus 2560 dispatches/layer. Both halves keep 240-wide phases.
// LDS: ys(16.1K) + hs(31.5K, o-tile overlaid) + ws(25.6K) = 73.4K.
// ---------------------------------------------------------------------------
__global__ __launch_bounds__(256) void k_pffn(
    const float* __restrict__ o, const float* __restrict__ proj_w,
    const float* __restrict__ proj_b, const float* __restrict__ g1,
    const float* __restrict__ be1,
    const float* __restrict__ w1, const float* __restrict__ b1,
    const float* __restrict__ w2, const float* __restrict__ b2,
    const float* __restrict__ g2, const float* __restrict__ be2,
    float* __restrict__ x) {
  int tok0 = blockIdx.x * 48, tid = threadIdx.x;
  __shared__ __align__(16) float ys[48 * XP * 4];   // normalized y (post-LN1)
  __shared__ __align__(16) float hs[48 * HP * 4];   // o-tile overlay, then h
  __shared__ __align__(16) float ws[80 * 80];
  __shared__ float mstd[96];

  float4* ys4 = (float4*)ys;
  float4* hs4 = (float4*)hs;
  float4* os4 = (float4*)hs;    // overlay (stride XP, 16.1K <= 31.5K)
  float4* ws4 = (float4*)ws;

  // --- Phase A: y = LN1(x + o @ proj_w + proj_b) ---
  const float4* ob4 = (const float4*)(o + (size_t)tok0 * 80);
  for (int i = tid; i < 960; i += 256) os4[(i / 20) * XP + (i % 20)] = ob4[i];
  for (int i = tid; i < 1600; i += 256)
    ws4[i] = *(const float4*)(proj_w + (i / 20) * 80 + (i % 20) * 4);
  __syncthreads();

  int tg = tid / 20, cg = tid % 20, t0 = tg * 4;
  {
    float acc[4][4] = {};
    if (tid < 240) {
      #pragma unroll
      for (int iq = 0; iq < 20; iq++) {
        float4 xv[4], wv[4];
        #pragma unroll
        for (int dt = 0; dt < 4; dt++) xv[dt] = os4[(t0 + dt) * XP + iq];
        #pragma unroll
        for (int di = 0; di < 4; di++) wv[di] = ws4[(iq * 4 + di) * 20 + cg];
        #pragma unroll
        for (int dt = 0; dt < 4; dt++) {
          const float* xp = (const float*)&xv[dt];
          #pragma unroll
          for (int di = 0; di < 4; di++) {
            const float* wp = (const float*)&wv[di];
            #pragma unroll
            for (int dc = 0; dc < 4; dc++) acc[dt][dc] += xp[di] * wp[dc];
          }
        }
      }
      float4 pb = *(const float4*)(proj_b + cg * 4);
      const float* pbp = (const float*)&pb;
      #pragma unroll
      for (int dt = 0; dt < 4; dt++) {
        float4 xr = *(const float4*)(x + (size_t)(tok0 + t0 + dt) * 80 + cg * 4);
        const float* xrp = (const float*)&xr;
        float4 out;
        out.x = acc[dt][0] + pbp[0] + xrp[0];
        out.y = acc[dt][1] + pbp[1] + xrp[1];
        out.z = acc[dt][2] + pbp[2] + xrp[2];
        out.w = acc[dt][3] + pbp[3] + xrp[3];
        ys4[(t0 + dt) * XP + cg] = out;
      }
    }
  }
  __syncthreads();
  if (tid < 48) {
    float s = 0.0f, s2 = 0.0f;
    #pragma unroll
    for (int iq = 0; iq < 20; iq++) {
      float4 v = ys4[tid * XP + iq];
      s  += v.x + v.y + v.z + v.w;
      s2 += v.x * v.x + v.y * v.y + v.z * v.z + v.w * v.w;
    }
    float mean = s / 80.0f;
    float var  = fmaxf(s2 / 80.0f - mean * mean, 0.0f);
    mstd[tid] = mean; mstd[48 + tid] = rsqrtf(var + 1e-5f);
  }
  __syncthreads();
  for (int e = tid; e < 960; e += 256) {
    int t = e / 20, c4 = e % 20;
    float4 v = ys4[t * XP + c4];
    float4 gg = *(const float4*)(g1 + c4 * 4);
    float4 bb = *(const float4*)(be1 + c4 * 4);
    float m = mstd[t], r = mstd[48 + t];
    v.x = (v.x - m) * r * gg.x + bb.x;
    v.y = (v.y - m) * r * gg.y + bb.y;
    v.z = (v.z - m) * r * gg.z + bb.z;
    v.w = (v.w - m) * r * gg.w + bb.w;
    ys4[t * XP + c4] = v;
  }

  // --- Phase B: h = gelu(y @ w1 + b1) ---
  for (int c0 = 0; c0 < 160; c0 += 80) {
    __syncthreads();   // normalize writes visible (1st iter); ws reads done
    for (int i = tid; i < 1600; i += 256)
      ws4[i] = *(const float4*)(w1 + (i / 20) * 160 + c0 + (i % 20) * 4);
    __syncthreads();
    if (tid < 240) {
      float acc[4][4] = {};
      #pragma unroll
      for (int iq = 0; iq < 20; iq++) {
        float4 xv[4], wv[4];
        #pragma unroll
        for (int dt = 0; dt < 4; dt++) xv[dt] = ys4[(t0 + dt) * XP + iq];
        #pragma unroll
        for (int di = 0; di < 4; di++) wv[di] = ws4[(iq * 4 + di) * 20 + cg];
        #pragma unroll
        for (int dt = 0; dt < 4; dt++) {
          const float* xp = (const float*)&xv[dt];
          #pragma unroll
          for (int di = 0; di < 4; di++) {
            const float* wp = (const float*)&wv[di];
            #pragma unroll
            for (int dc = 0; dc < 4; dc++) acc[dt][dc] += xp[di] * wp[dc];
          }
        }
      }
      float4 bb = *(const float4*)(b1 + c0 + cg * 4);
      const float* bp = (const float*)&bb;
      #pragma unroll
      for (int dt = 0; dt < 4; dt++) {
        float4 out;
        float* op = (float*)&out;
        #pragma unroll
        for (int dc = 0; dc < 4; dc++)
          op[dc] = gelu_f(acc[dt][dc] + bp[dc]);
        hs4[(t0 + dt) * HP + c0 / 4 + cg] = out;
      }
    }
  }

  // --- Phase C: out = LN2(y + h @ w2 + b2) ---
  float acc[4][4] = {};
  for (int k0 = 0; k0 < 160; k0 += 80) {
    __syncthreads();
    for (int i = tid; i < 1600; i += 256)
      ws4[i] = *(const float4*)(w2 + (size_t)(k0 + i / 20) * 80 + (i % 20) * 4);
    __syncthreads();
    if (tid < 240) {
      #pragma unroll
      for (int iq = 0; iq < 20; iq++) {
        float4 hv[4], wv[4];
        #pragma unroll
        for (int dt = 0; dt < 4; dt++) hv[dt] = hs4[(t0 + dt) * HP + k0 / 4 + iq];
        #pragma unroll
        for (int di = 0; di < 4; di++) wv[di] = ws4[(iq * 4 + di) * 20 + cg];
        #pragma unroll
        for (int dt = 0; dt < 4; dt++) {
          const float* hp = (const float*)&hv[dt];
          #pragma unroll
          for (int di = 0; di < 4; di++) {
            const float* wp = (const float*)&wv[di];
            #pragma unroll
            for (int dc = 0; dc < 4; dc++) acc[dt][dc] += hp[di] * wp[dc];
          }
        }
      }
    }
  }
  __syncthreads();
  if (tid < 240) {
    float4 bb = *(const float4*)(b2 + cg * 4);
    const float* bp = (const float*)&bb;
    #pragma unroll
    for (int dt = 0; dt < 4; dt++) {
      float4 xr = ys4[(t0 + dt) * XP + cg];   // residual = normalized y
      const float* xrp = (const float*)&xr;
      float4 out;
      out.x = acc[dt][0] + bp[0] + xrp[0];
      out.y = acc[dt][1] + bp[1] + xrp[1];
      out.z = acc[dt][2] + bp[2] + xrp[2];
      out.w = acc[dt][3] + bp[3] + xrp[3];
      hs4[(t0 + dt) * HP + cg] = out;
    }
  }
  __syncthreads();
  if (tid < 48) {
    float s = 0.0f, s2 = 0.0f;
    #pragma unroll
    for (int iq = 0; iq < 20; iq++) {
      float4 v = hs4[tid * HP + iq];
      s  += v.x + v.y + v.z + v.w;
      s2 += v.x * v.x + v.y * v.y + v.z * v.z + v.w * v.w;
    }
    float mean = s / 80.0f;
    float var  = fmaxf(s2 / 80.0f - mean * mean, 0.0f);
    mstd[tid] = mean; mstd[48 + tid] = rsqrtf(var + 1e-5f);
  }
  __syncthreads();
  for (int e = tid; e < 960; e += 256) {
    int t = e / 20, c4 = e % 20;
    float4 v = hs4[t * HP + c4];
    float4 gg = *(const float4*)(g2 + c4 * 4);
    float4 bb = *(const float4*)(be2 + c4 * 4);
    float m = mstd[t], r = mstd[48 + t];
    float4 out;
    out.x = (v.x - m) * r * gg.x + bb.x;
    out.y = (v.y - m) * r * gg.y + bb.y;
    out.z = (v.z - m) * r * gg.z + bb.z;
    out.w = (v.w - m) * r * gg.w + bb.w;
    ((float4*)(x + (size_t)tok0 * 80))[e] = out;
  }
}

// ---------------------------------------------------------------------------
// K5: final LN at gathered position + fnorm + h1 = gelu(final@pr_w1+pr_b1)
// ---------------------------------------------------------------------------
__global__ __launch_bounds__(128) void k_final(
    const float* __restrict__ x, const int* __restrict__ seq_len,
    const float* __restrict__ fn_g, const float* __restrict__ fn_b,
    const float* __restrict__ pr_w1, const float* __restrict__ pr_b1,
    float* __restrict__ fnorm, float* __restrict__ h1) {
  int b = blockIdx.x, tid = threadIdx.x;
  __shared__ float red[128], red2[128];
  __shared__ float fbuf[DD];
  int t = seq_len[b] - 1; t = min(max(t, 0), LL - 1);
  float v = 0.0f;
  if (tid < DD) v = x[((size_t)b * LL + t) * DD + tid];
  red[tid]  = (tid < DD) ? v : 0.0f;
  red2[tid] = (tid < DD) ? v * v : 0.0f;
  __syncthreads();
  for (int s = 64; s > 0; s >>= 1) {
    if (tid < s) { red[tid] += red[tid + s]; red2[tid] += red2[tid + s]; }
    __syncthreads();
  }
  float mean = red[0] / DD;
  float var  = fmaxf(red2[0] / DD - mean * mean, 0.0f);
  float rstd = rsqrtf(var + 1e-5f);
  float f = 0.0f;
  if (tid < DD) { f = (v - mean) * rstd * fn_g[tid] + fn_b[tid]; fbuf[tid] = f; }
  __syncthreads();
  red[tid] = (tid < DD) ? f * f : 0.0f;
  __syncthreads();
  for (int s = 64; s > 0; s >>= 1) {
    if (tid < s) red[tid] += red[tid + s];
    __syncthreads();
  }
  float rn = 1.0f / fmaxf(sqrtf(red[0]), 1e-12f);
  if (tid < DD) {
    fnorm[(size_t)b * DD + tid] = f * rn;
    float gacc = pr_b1[tid];
    for (int i = 0; i < DD; i++) gacc += fbuf[i] * pr_w1[i * DD + tid];
    h1[(size_t)b * DD + tid] = gelu_f(gacc);
  }
}

// ---------------------------------------------------------------------------
// K6: normalize proto rows -> transposed pnormT[k][c]
// ---------------------------------------------------------------------------
__global__ __launch_bounds__(128) void k_pnorm(
    const float* __restrict__ protos, float* __restrict__ pnormT) {
  int c = blockIdx.x, tid = threadIdx.x;
  __shared__ float red[128];
  float v = 0.0f;
  if (tid < DD) v = protos[(size_t)c * DD + tid];
  red[tid] = (tid < DD) ? v * v : 0.0f;
  __syncthreads();
  for (int s = 64; s > 0; s >>= 1) {
    if (tid < s) red[tid] += red[tid + s];
    __syncthreads();
  }
  float rn = 1.0f / fmaxf(sqrtf(red[0]), 1e-12f);
  if (tid < DD) pnormT[(size_t)tid * NLOC + c] = v * rn;
}

// ---------------------------------------------------------------------------
// K7: logits — 4 batch rows per block
// ---------------------------------------------------------------------------
__global__ __launch_bounds__(256) void k_logits(
    const float* __restrict__ h1, const float* __restrict__ fnorm,
    const float* __restrict__ pr_w2, const float* __restrict__ pr_b2,
    const float* __restrict__ pnormT, const float* __restrict__ temp,
    float* __restrict__ out) {
  int b0 = (blockIdx.x / 5) * 4, cb = blockIdx.x % 5;
  int tid = threadIdx.x;
  int c = cb * 256 + tid;
  __shared__ float h1s[4][DD], fns[4][DD];
  for (int i = tid; i < 4 * DD; i += 256) {
    int j = i / DD, k = i % DD;
    h1s[j][k] = h1[(size_t)(b0 + j) * DD + k];
    fns[j][k] = fnorm[(size_t)(b0 + j) * DD + k];
  }
  __syncthreads();
  if (c < NLOC) {
    float a1[4] = {0, 0, 0, 0}, a2[4] = {0, 0, 0, 0};
    for (int k = 0; k < DD; k++) {
      float w = pr_w2[(size_t)k * NLOC + c];
      float p = pnormT[(size_t)k * NLOC + c];
      #pragma unroll
      for (int j = 0; j < 4; j++) {
        a1[j] += h1s[j][k] * w;
        a2[j] += fns[j][k] * p;
      }
    }
    float pb = pr_b2[c];
    float tt = fminf(fmaxf(temp[0], 0.5f), 3.0f);
    #pragma unroll
    for (int j = 0; j < 4; j++)
      out[(size_t)(b0 + j) * NLOC + c] = (0.5f * (a1[j] + pb) + 7.5f * a2[j]) / tt;
  }
}

// ---------------------------------------------------------------------------
extern "C" void kernel_launch(void* const* d_in, const int* in_sizes, int n_in,
                              void* d_out, int out_size, void* d_ws, size_t ws_size,
                              hipStream_t stream) {
  const int* loc_seq   = (const int*)d_in[0];
  const int* user_seq  = (const int*)d_in[1];
  const int* wk_seq    = (const int*)d_in[2];
  const int* sm_seq    = (const int*)d_in[3];
  const int* dur_seq   = (const int*)d_in[4];
  const int* diff_seq  = (const int*)d_in[5];
  const int* seq_len   = (const int*)d_in[6];
  const float* loc_table = (const float*)d_in[7];
  const float* user_table= (const float*)d_in[8];
  const float* wk_table  = (const float*)d_in[9];
  const float* hr_table  = (const float*)d_in[10];
  const float* in_w   = (const float*)d_in[11];
  const float* in_b   = (const float*)d_in[12];
  const float* in_g   = (const float*)d_in[13];
  const float* in_be  = (const float*)d_in[14];
  const float* pos_emb= (const float*)d_in[15];
  const float* qkv_w  = (const float*)d_in[16];
  const float* proj_w = (const float*)d_in[17];
  const float* proj_b = (const float*)d_in[18];
  const float* rel_emb= (const float*)d_in[19];
  const float* n1_g   = (const float*)d_in[20];
  const float* n1_b   = (const float*)d_in[21];
  const float* ffn_w1 = (const float*)d_in[22];
  const float* ffn_b1 = (const float*)d_in[23];
  const float* ffn_w2 = (const float*)d_in[24];
  const float* ffn_b2 = (const float*)d_in[25];
  const float* n2_g   = (const float*)d_in[26];
  const float* n2_b   = (const float*)d_in[27];
  const float* fn_g   = (const float*)d_in[28];
  const float* fn_b   = (const float*)d_in[29];
  const float* pr_w1  = (const float*)d_in[30];
  const float* pr_b1  = (const float*)d_in[31];
  const float* pr_w2  = (const float*)d_in[32];
  const float* pr_b2  = (const float*)d_in[33];
  const float* protos = (const float*)d_in[34];
  const float* temp   = (const float*)d_in[35];
  float* out = (float*)d_out;

  float* x      = (float*)d_ws;
  float* o      = x + (size_t)BB * LL * DD;
  float* qkvo   = o + (size_t)BB * LL * DD;
  float* fnorm  = qkvo + (size_t)BB * 14400;
  float* h1     = fnorm + (size_t)BB * DD;
  float* pnormT = h1 + (size_t)BB * DD;
  float* relTg  = pnormT + (size_t)DD * NLOC;   // 3600 floats

  k_rprep<<<15, 256, 0, stream>>>(rel_emb, relTg);

  k_embed<<<BB * LL / 48, 256, 0, stream>>>(loc_seq, user_seq, wk_seq, sm_seq,
                                            dur_seq, diff_seq, loc_table,
                                            user_table, wk_table, hr_table,
                                            in_w, in_b, in_g, in_be, pos_emb, x);

  for (int l = 0; l < NLNUM; l++) {
    k_qkv<<<BB, 256, 0, stream>>>(x, qkv_w + (size_t)l * 80 * 240, qkvo);
    k_attn<<<BB * HH, 256, 0, stream>>>(qkvo, loc_seq,
                                        relTg + (size_t)l * 1200, o);
    k_pffn<<<BB * LL / 48, 256, 0, stream>>>(
        o, proj_w + (size_t)l * DD * DD, proj_b + (size_t)l * DD,
        n1_g + (size_t)l * DD, n1_b + (size_t)l * DD,
        ffn_w1 + (size_t)l * DD * DFF, ffn_b1 + (size_t)l * DFF,
        ffn_w2 + (size_t)l * DFF * DD, ffn_b2 + (size_t)l * DD,
        n2_g + (size_t)l * DD, n2_b + (size_t)l * DD, x);
  }

  k_pnorm<<<NLOC, 128, 0, stream>>>(protos, pnormT);
  k_final<<<BB, 128, 0, stream>>>(x, seq_len, fn_g, fn_b, pr_w1, pr_b1, fnorm, h1);
  k_logits<<<(BB / 4) * 5, 256, 0, stream>>>(h1, fnorm, pr_w2, pr_b2, pnormT, temp, out);
}

// Round 15
// 1526.450 us; speedup vs baseline: 1.1356x; 1.0590x over previous
//
#include <hip/hip_runtime.h>
#include <hip/hip_bf16.h>
#include <math.h>

#define BB   2048
#define LL   60
#define DD   80
#define HH   8
#define HDD  10
#define NLNUM 3
#define NLOC 1187
#define DFF  160
#define IN_DIM 138
#define RELN 119
#define SCS  68   // sc row stride (floats): 68 mod 32 = 4 -> rows spread banks
#define XP   21   // padded tile row stride in float4 (84 words, !=0 mod 32)
#define HP   41   // padded h-tile row stride in float4 (164 words)
#define VP   35   // vin row stride in float4 (140 words)
#define TS   65   // xsT row stride in float4 (260 words, 260 mod 32 = 4)

// Branchless gelu: erf via Abramowitz-Stegun 7.1.26 (|err| <= 1.5e-7).
__device__ __forceinline__ float gelu_f(float a) {
  float x = fabsf(a) * 0.70710678118654752f;
  float t = 1.0f / (1.0f + 0.3275911f * x);
  float y = t * (0.254829592f + t * (-0.284496736f + t * (1.421413741f +
            t * (-1.453152027f + t * 1.061405429f))));
  float e = 1.0f - y * __expf(-x * x);           // erf(|x|)
  float erf_s = copysignf(e, a);
  return 0.5f * a * (1.0f + erf_s);
}

// ---------------------------------------------------------------------------
// K0: pre-transpose rel_emb [l][p:119][d:10] -> relTg [l][d:10][p:120]
// ---------------------------------------------------------------------------
__global__ __launch_bounds__(256) void k_rprep(
    const float* __restrict__ rel_emb, float* __restrict__ relTg) {
  int idx = blockIdx.x * 256 + threadIdx.x;   // 3*10*120 = 3600
  if (idx >= 3600) return;
  int p = idx % 120;
  int d = (idx / 120) % 10;
  int l = idx / 1200;
  float v = 0.0f;
  if (p < RELN) v = rel_emb[l * RELN * HDD + p * HDD + d];
  relTg[idx] = v;
}

// ---------------------------------------------------------------------------
// K1: embed+inproj+LN as a 48-token GEMM block
// ---------------------------------------------------------------------------
__global__ __launch_bounds__(256) void k_embed(
    const int* __restrict__ loc_seq, const int* __restrict__ user_seq,
    const int* __restrict__ wk_seq, const int* __restrict__ sm_seq,
    const int* __restrict__ dur_seq, const int* __restrict__ diff_seq,
    const float* __restrict__ loc_table, const float* __restrict__ user_table,
    const float* __restrict__ wk_table, const float* __restrict__ hr_table,
    const float* __restrict__ in_w, const float* __restrict__ in_b,
    const float* __restrict__ in_g, const float* __restrict__ in_be,
    const float* __restrict__ pos_emb, float* __restrict__ x) {
  int tok0 = blockIdx.x * 48, tid = threadIdx.x;
  __shared__ __align__(16) float vin[48 * VP * 4];
  __shared__ __align__(16) float ws[140 * 80];
  __shared__ float mstd[96];

  float4* vin4 = (float4*)vin;
  float4* ws4  = (float4*)ws;

  for (int i = tid; i < 140 * 20; i += 256) {
    int r = i / 20, c = i % 20;
    float4 v = make_float4(0.0f, 0.0f, 0.0f, 0.0f);
    if (r < IN_DIM) v = *(const float4*)(in_w + r * 80 + c * 4);
    ws4[i] = v;
  }
  for (int i = tid; i < 48 * 35; i += 256) {
    int t = i / 35, s = i % 35;
    int tok = tok0 + t;
    float4 v;
    if (s < 20) {
      int loc = loc_seq[tok];
      v = *(const float4*)(loc_table + (size_t)loc * 80 + s * 4);
    } else if (s < 26) {
      int usr = user_seq[(tok / LL) * LL];
      v = *(const float4*)(user_table + usr * 24 + (s - 20) * 4);
    } else if (s < 30) {
      int wk = wk_seq[tok];
      v = *(const float4*)(wk_table + wk * 16 + (s - 26) * 4);
    } else if (s < 34) {
      int hr = sm_seq[tok] / 60; hr = min(max(hr, 0), 23);
      v = *(const float4*)(hr_table + hr * 16 + (s - 30) * 4);
    } else {
      v.x = (float)diff_seq[tok] / 10.0f;
      v.y = (float)dur_seq[tok] / 300.0f;
      v.z = 0.0f; v.w = 0.0f;
    }
    vin4[t * VP + s] = v;
  }
  __syncthreads();

  int tg = tid / 20, cg = tid % 20, t0 = tg * 4;
  float acc[4][4] = {};
  if (tid < 240) {
    #pragma unroll 7
    for (int iq = 0; iq < 35; iq++) {
      float4 xv[4], wv[4];
      #pragma unroll
      for (int dt = 0; dt < 4; dt++) xv[dt] = vin4[(t0 + dt) * VP + iq];
      #pragma unroll
      for (int di = 0; di < 4; di++) wv[di] = ws4[(iq * 4 + di) * 20 + cg];
      #pragma unroll
      for (int dt = 0; dt < 4; dt++) {
        const float* xp = (const float*)&xv[dt];
        #pragma unroll
        for (int di = 0; di < 4; di++) {
          const float* wp = (const float*)&wv[di];
          #pragma unroll
          for (int dc = 0; dc < 4; dc++) acc[dt][dc] += xp[di] * wp[dc];
        }
      }
    }
  }
  __syncthreads();
  if (tid < 240) {
    float4 bb = *(const float4*)(in_b + cg * 4);
    const float* bp = (const float*)&bb;
    #pragma unroll
    for (int dt = 0; dt < 4; dt++) {
      float4 y;
      y.x = acc[dt][0] + bp[0];
      y.y = acc[dt][1] + bp[1];
      y.z = acc[dt][2] + bp[2];
      y.w = acc[dt][3] + bp[3];
      vin4[(t0 + dt) * VP + cg] = y;
    }
  }
  __syncthreads();
  if (tid < 48) {
    float s = 0.0f, s2 = 0.0f;
    #pragma unroll
    for (int iq = 0; iq < 20; iq++) {
      float4 v = vin4[tid * VP + iq];
      s  += v.x + v.y + v.z + v.w;
      s2 += v.x * v.x + v.y * v.y + v.z * v.z + v.w * v.w;
    }
    float mean = s / 80.0f;
    float var  = fmaxf(s2 / 80.0f - mean * mean, 0.0f);
    mstd[tid] = mean; mstd[48 + tid] = rsqrtf(var + 1e-5f);
  }
  __syncthreads();
  for (int e = tid; e < 960; e += 256) {
    int t = e / 20, c4 = e % 20;
    float4 v = vin4[t * VP + c4];
    float4 gg = *(const float4*)(in_g + c4 * 4);
    float4 bb = *(const float4*)(in_be + c4 * 4);
    float4 pe = *(const float4*)(pos_emb + ((tok0 + t) % LL) * 80 + c4 * 4);
    float m = mstd[t], r = mstd[48 + t];
    float4 out;
    out.x = (v.x - m) * r * gg.x + bb.x + pe.x;
    out.y = (v.y - m) * r * gg.y + bb.y + pe.y;
    out.z = (v.z - m) * r * gg.z + bb.z + pe.z;
    out.w = (v.w - m) * r * gg.w + bb.w + pe.w;
    ((float4*)(x + (size_t)tok0 * 80))[e] = out;
  }
}

// ---------------------------------------------------------------------------
// K2a: qkv GEMM per batch row b -> qkvo[b][c][t].
// v2: t-fast tile mapping (tg=tid%15) so 15 consecutive lanes write 240 B
// contiguous runs (was 64 scattered 16-B writes/wave); x staged TRANSPOSED
// xsT[iq][t] (stride 65 f4 = 260 words, 4 mod 32) so GEMM reads are
// lane-consecutive; 60-col weight chunks -> 225 tiles/pass, 40 KB LDS
// (4 blocks/CU, was 3).
// ---------------------------------------------------------------------------
__global__ __launch_bounds__(256) void k_qkv(
    const float* __restrict__ x, const float* __restrict__ qkv_w,
    float* __restrict__ qkvo) {
  int b = blockIdx.x, tid = threadIdx.x;
  __shared__ __align__(16) float xsT[20 * TS * 4];   // 20.8 KB  [iq][t]
  __shared__ __align__(16) float ws[80 * 60];        // 19.2 KB  [i][c4:15]

  const float4* xb4 = (const float4*)(x + (size_t)b * 4800);
  float4* xsT4 = (float4*)xsT;
  float4* ws4  = (float4*)ws;
  for (int i = tid; i < 1200; i += 256) {
    int t = i / 20, iq = i % 20;
    xsT4[iq * TS + t] = xb4[i];
  }

  for (int c0 = 0; c0 < 240; c0 += 60) {
    __syncthreads();
    for (int i = tid; i < 1200; i += 256)
      ws4[i] = *(const float4*)(qkv_w + (i / 15) * 240 + c0 + (i % 15) * 4);
    __syncthreads();
    if (tid < 225) {
      int tg = tid % 15, cg = tid / 15;
      int t0 = tg * 4;
      float acc[4][4] = {};   // [dt][dc]
      #pragma unroll 5
      for (int iq = 0; iq < 20; iq++) {
        float4 xv[4], wv[4];
        #pragma unroll
        for (int dt = 0; dt < 4; dt++) xv[dt] = xsT4[iq * TS + t0 + dt];
        #pragma unroll
        for (int di = 0; di < 4; di++) wv[di] = ws4[(iq * 4 + di) * 15 + cg];
        #pragma unroll
        for (int dt = 0; dt < 4; dt++) {
          const float* xp = (const float*)&xv[dt];
          #pragma unroll
          for (int di = 0; di < 4; di++) {
            const float* wp = (const float*)&wv[di];
            #pragma unroll
            for (int dc = 0; dc < 4; dc++) acc[dt][dc] += xp[di] * wp[dc];
          }
        }
      }
      float* qb = qkvo + (size_t)b * 14400 + (size_t)(c0 + cg * 4) * 60 + t0;
      #pragma unroll
      for (int dc = 0; dc < 4; dc++)
        *(float4*)(qb + dc * 60) =
            make_float4(acc[0][dc], acc[1][dc], acc[2][dc], acc[3][dc]);
    }
  }
}

// ---------------------------------------------------------------------------
// K2b: attention per (b,h), 256 threads; relT staged via coalesced relTg.
// ---------------------------------------------------------------------------
__global__ __launch_bounds__(256) void k_attn(
    const float* __restrict__ qkvo, const int* __restrict__ loc_seq,
    const float* __restrict__ relTg,   // layer slice [10][120]
    float* __restrict__ o) {
  int bh = blockIdx.x;
  int b = bh >> 3, h = bh & 7;
  int tid = threadIdx.x;

  __shared__ __align__(16) float qs[HDD * 60];
  __shared__ __align__(16) float ks[HDD * 60];
  __shared__ __align__(16) float vs[HDD * 60];
  __shared__ __align__(16) float relT[HDD * 120];
  __shared__ __align__(16) float sc[60 * SCS];
  __shared__ __align__(16) float rsum[64];
  __shared__ float msk[60];

  const float4* src = (const float4*)(qkvo + (size_t)b * 14400);
  float4* q4 = (float4*)qs; float4* k4 = (float4*)ks; float4* v4 = (float4*)vs;
  for (int i = tid; i < 150; i += 256) {
    q4[i] = src[h * 150 + i];
    k4[i] = src[1200 + h * 150 + i];
    v4[i] = src[2400 + h * 150 + i];
  }
  const float4* rg4 = (const float4*)relTg;
  float4* relT4 = (float4*)relT;
  for (int i = tid; i < 300; i += 256) relT4[i] = rg4[i];
  if (tid < 60) msk[tid] = (loc_seq[b * LL + tid] == 0) ? 1.0f : 0.0f;
  __syncthreads();

  if (tid < 225) {
    int ig = tid / 15, jg = tid % 15;
    int i0 = ig * 4, j0 = jg * 4;
    int w0 = j0 - i0 + 56;
    float acc[4][4] = {};
    #pragma unroll
    for (int d = 0; d < 10; d++) {
      float4 qv = *(const float4*)(qs + d * 60 + i0);
      float4 kv = *(const float4*)(ks + d * 60 + j0);
      float4 rA = *(const float4*)(relT + d * 120 + w0);
      float4 rB = *(const float4*)(relT + d * 120 + w0 + 4);
      float rr[8] = {rA.x, rA.y, rA.z, rA.w, rB.x, rB.y, rB.z, rB.w};
      const float* qp = (const float*)&qv;
      const float* kp = (const float*)&kv;
      #pragma unroll
      for (int di = 0; di < 4; di++)
        #pragma unroll
        for (int dj = 0; dj < 4; dj++)
          acc[di][dj] += qp[di] * (kp[dj] + rr[dj - di + 3]);
    }
    const float scale = 0.31622776601683794f;
    #pragma unroll
    for (int di = 0; di < 4; di++) {
      #pragma unroll
      for (int dj = 0; dj < 4; dj++) {
        float v = acc[di][dj] * scale;
        if (msk[j0 + dj] != 0.0f) v = -1e30f;
        acc[di][dj] = v;
      }
      *(float4*)(sc + (i0 + di) * SCS + j0) =
          make_float4(acc[di][0], acc[di][1], acc[di][2], acc[di][3]);
    }
  }
  __syncthreads();

  if (tid < 60) {
    float* row = sc + tid * SCS;
    int c = (tid >> 3) & 7;
    float m0 = -3.0e38f, m1 = -3.0e38f, m2 = -3.0e38f, m3 = -3.0e38f;
    #pragma unroll
    for (int s = 0; s < 15; s++) {
      int k = c + s; if (k >= 15) k -= 15;
      float4 v = *(const float4*)(row + 4 * k);
      m0 = fmaxf(m0, v.x); m1 = fmaxf(m1, v.y);
      m2 = fmaxf(m2, v.z); m3 = fmaxf(m3, v.w);
    }
    float m = fmaxf(fmaxf(m0, m1), fmaxf(m2, m3));
    float s0 = 0.0f, s1 = 0.0f, s2 = 0.0f, s3 = 0.0f;
    #pragma unroll
    for (int s = 0; s < 15; s++) {
      int k = c + s; if (k >= 15) k -= 15;
      float4 v = *(float4*)(row + 4 * k);
      v.x = __expf(v.x - m); v.y = __expf(v.y - m);
      v.z = __expf(v.z - m); v.w = __expf(v.w - m);
      *(float4*)(row + 4 * k) = v;
      s0 += v.x; s1 += v.y; s2 += v.z; s3 += v.w;
    }
    rsum[tid] = 1.0f / (s0 + s1 + s2 + s3);
  }
  __syncthreads();

  if (tid < 150) {
    int ig = tid / 10, d = tid % 10;
    float acc[4] = {0, 0, 0, 0};
    #pragma unroll 5
    for (int jq = 0; jq < 15; jq++) {
      float4 vv = *(const float4*)(vs + d * 60 + jq * 4);
      #pragma unroll
      for (int di = 0; di < 4; di++) {
        float4 av = *(const float4*)(sc + (ig + 15 * di) * SCS + jq * 4);
        acc[di] += av.x * vv.x + av.y * vv.y + av.z * vv.z + av.w * vv.w;
      }
    }
    #pragma unroll
    for (int di = 0; di < 4; di++) {
      float r = rsum[ig + 15 * di];
      o[((size_t)b * 60 + ig + 15 * di) * 80 + h * 10 + d] = acc[di] * r;
    }
  }
}

// ---------------------------------------------------------------------------
// K3: fused proj+LN1+FFN+LN2 — 48 tokens/block.
// ---------------------------------------------------------------------------
__global__ __launch_bounds__(256) void k_pffn(
    const float* __restrict__ o, const float* __restrict__ proj_w,
    const float* __restrict__ proj_b, const float* __restrict__ g1,
    const float* __restrict__ be1,
    const float* __restrict__ w1, const float* __restrict__ b1,
    const float* __restrict__ w2, const float* __restrict__ b2,
    const float* __restrict__ g2, const float* __restrict__ be2,
    float* __restrict__ x) {
  int tok0 = blockIdx.x * 48, tid = threadIdx.x;
  __shared__ __align__(16) float ys[48 * XP * 4];   // normalized y (post-LN1)
  __shared__ __align__(16) float hs[48 * HP * 4];   // o-tile overlay, then h
  __shared__ __align__(16) float ws[80 * 80];
  __shared__ float mstd[96];

  float4* ys4 = (float4*)ys;
  float4* hs4 = (float4*)hs;
  float4* os4 = (float4*)hs;    // overlay (stride XP)
  float4* ws4 = (float4*)ws;

  // --- Phase A: y = LN1(x + o @ proj_w + proj_b) ---
  const float4* ob4 = (const float4*)(o + (size_t)tok0 * 80);
  for (int i = tid; i < 960; i += 256) os4[(i / 20) * XP + (i % 20)] = ob4[i];
  for (int i = tid; i < 1600; i += 256)
    ws4[i] = *(const float4*)(proj_w + (i / 20) * 80 + (i % 20) * 4);
  __syncthreads();

  int tg = tid / 20, cg = tid % 20, t0 = tg * 4;
  {
    float acc[4][4] = {};
    if (tid < 240) {
      #pragma unroll
      for (int iq = 0; iq < 20; iq++) {
        float4 xv[4], wv[4];
        #pragma unroll
        for (int dt = 0; dt < 4; dt++) xv[dt] = os4[(t0 + dt) * XP + iq];
        #pragma unroll
        for (int di = 0; di < 4; di++) wv[di] = ws4[(iq * 4 + di) * 20 + cg];
        #pragma unroll
        for (int dt = 0; dt < 4; dt++) {
          const float* xp = (const float*)&xv[dt];
          #pragma unroll
          for (int di = 0; di < 4; di++) {
            const float* wp = (const float*)&wv[di];
            #pragma unroll
            for (int dc = 0; dc < 4; dc++) acc[dt][dc] += xp[di] * wp[dc];
          }
        }
      }
      float4 pb = *(const float4*)(proj_b + cg * 4);
      const float* pbp = (const float*)&pb;
      #pragma unroll
      for (int dt = 0; dt < 4; dt++) {
        float4 xr = *(const float4*)(x + (size_t)(tok0 + t0 + dt) * 80 + cg * 4);
        const float* xrp = (const float*)&xr;
        float4 out;
        out.x = acc[dt][0] + pbp[0] + xrp[0];
        out.y = acc[dt][1] + pbp[1] + xrp[1];
        out.z = acc[dt][2] + pbp[2] + xrp[2];
        out.w = acc[dt][3] + pbp[3] + xrp[3];
        ys4[(t0 + dt) * XP + cg] = out;
      }
    }
  }
  __syncthreads();
  if (tid < 48) {
    float s = 0.0f, s2 = 0.0f;
    #pragma unroll
    for (int iq = 0; iq < 20; iq++) {
      float4 v = ys4[tid * XP + iq];
      s  += v.x + v.y + v.z + v.w;
      s2 += v.x * v.x + v.y * v.y + v.z * v.z + v.w * v.w;
    }
    float mean = s / 80.0f;
    float var  = fmaxf(s2 / 80.0f - mean * mean, 0.0f);
    mstd[tid] = mean; mstd[48 + tid] = rsqrtf(var + 1e-5f);
  }
  __syncthreads();
  for (int e = tid; e < 960; e += 256) {
    int t = e / 20, c4 = e % 20;
    float4 v = ys4[t * XP + c4];
    float4 gg = *(const float4*)(g1 + c4 * 4);
    float4 bb = *(const float4*)(be1 + c4 * 4);
    float m = mstd[t], r = mstd[48 + t];
    v.x = (v.x - m) * r * gg.x + bb.x;
    v.y = (v.y - m) * r * gg.y + bb.y;
    v.z = (v.z - m) * r * gg.z + bb.z;
    v.w = (v.w - m) * r * gg.w + bb.w;
    ys4[t * XP + c4] = v;
  }

  // --- Phase B: h = gelu(y @ w1 + b1) ---
  for (int c0 = 0; c0 < 160; c0 += 80) {
    __syncthreads();
    for (int i = tid; i < 1600; i += 256)
      ws4[i] = *(const float4*)(w1 + (i / 20) * 160 + c0 + (i % 20) * 4);
    __syncthreads();
    if (tid < 240) {
      float acc[4][4] = {};
      #pragma unroll
      for (int iq = 0; iq < 20; iq++) {
        float4 xv[4], wv[4];
        #pragma unroll
        for (int dt = 0; dt < 4; dt++) xv[dt] = ys4[(t0 + dt) * XP + iq];
        #pragma unroll
        for (int di = 0; di < 4; di++) wv[di] = ws4[(iq * 4 + di) * 20 + cg];
        #pragma unroll
        for (int dt = 0; dt < 4; dt++) {
          const float* xp = (const float*)&xv[dt];
          #pragma unroll
          for (int di = 0; di < 4; di++) {
            const float* wp = (const float*)&wv[di];
            #pragma unroll
            for (int dc = 0; dc < 4; dc++) acc[dt][dc] += xp[di] * wp[dc];
          }
        }
      }
      float4 bb = *(const float4*)(b1 + c0 + cg * 4);
      const float* bp = (const float*)&bb;
      #pragma unroll
      for (int dt = 0; dt < 4; dt++) {
        float4 out;
        float* op = (float*)&out;
        #pragma unroll
        for (int dc = 0; dc < 4; dc++)
          op[dc] = gelu_f(acc[dt][dc] + bp[dc]);
        hs4[(t0 + dt) * HP + c0 / 4 + cg] = out;
      }
    }
  }

  // --- Phase C: out = LN2(y + h @ w2 + b2) ---
  float acc[4][4] = {};
  for (int k0 = 0; k0 < 160; k0 += 80) {
    __syncthreads();
    for (int i = tid; i < 1600; i += 256)
      ws4[i] = *(const float4*)(w2 + (size_t)(k0 + i / 20) * 80 + (i % 20) * 4);
    __syncthreads();
    if (tid < 240) {
      #pragma unroll
      for (int iq = 0; iq < 20; iq++) {
        float4 hv[4], wv[4];
        #pragma unroll
        for (int dt = 0; dt < 4; dt++) hv[dt] = hs4[(t0 + dt) * HP + k0 / 4 + iq];
        #pragma unroll
        for (int di = 0; di < 4; di++) wv[di] = ws4[(iq * 4 + di) * 20 + cg];
        #pragma unroll
        for (int dt = 0; dt < 4; dt++) {
          const float* hp = (const float*)&hv[dt];
          #pragma unroll
          for (int di = 0; di < 4; di++) {
            const float* wp = (const float*)&wv[di];
            #pragma unroll
            for (int dc = 0; dc < 4; dc++) acc[dt][dc] += hp[di] * wp[dc];
          }
        }
      }
    }
  }
  __syncthreads();
  if (tid < 240) {
    float4 bb = *(const float4*)(b2 + cg * 4);
    const float* bp = (const float*)&bb;
    #pragma unroll
    for (int dt = 0; dt < 4; dt++) {
      float4 xr = ys4[(t0 + dt) * XP + cg];   // residual = normalized y
      const float* xrp = (const float*)&xr;
      float4 out;
      out.x = acc[dt][0] + bp[0] + xrp[0];
      out.y = acc[dt][1] + bp[1] + xrp[1];
      out.z = acc[dt][2] + bp[2] + xrp[2];
      out.w = acc[dt][3] + bp[3] + xrp[3];
      hs4[(t0 + dt) * HP + cg] = out;
    }
  }
  __syncthreads();
  if (tid < 48) {
    float s = 0.0f, s2 = 0.0f;
    #pragma unroll
    for (int iq = 0; iq < 20; iq++) {
      float4 v = hs4[tid * HP + iq];
      s  += v.x + v.y + v.z + v.w;
      s2 += v.x * v.x + v.y * v.y + v.z * v.z + v.w * v.w;
    }
    float mean = s / 80.0f;
    float var  = fmaxf(s2 / 80.0f - mean * mean, 0.0f);
    mstd[tid] = mean; mstd[48 + tid] = rsqrtf(var + 1e-5f);
  }
  __syncthreads();
  for (int e = tid; e < 960; e += 256) {
    int t = e / 20, c4 = e % 20;
    float4 v = hs4[t * HP + c4];
    float4 gg = *(const float4*)(g2 + c4 * 4);
    float4 bb = *(const float4*)(be2 + c4 * 4);
    float m = mstd[t], r = mstd[48 + t];
    float4 out;
    out.x = (v.x - m) * r * gg.x + bb.x;
    out.y = (v.y - m) * r * gg.y + bb.y;
    out.z = (v.z - m) * r * gg.z + bb.z;
    out.w = (v.w - m) * r * gg.w + bb.w;
    ((float4*)(x + (size_t)tok0 * 80))[e] = out;
  }
}

// ---------------------------------------------------------------------------
// K5: final LN at gathered position + fnorm + h1 = gelu(final@pr_w1+pr_b1)
// ---------------------------------------------------------------------------
__global__ __launch_bounds__(128) void k_final(
    const float* __restrict__ x, const int* __restrict__ seq_len,
    const float* __restrict__ fn_g, const float* __restrict__ fn_b,
    const float* __restrict__ pr_w1, const float* __restrict__ pr_b1,
    float* __restrict__ fnorm, float* __restrict__ h1) {
  int b = blockIdx.x, tid = threadIdx.x;
  __shared__ float red[128], red2[128];
  __shared__ float fbuf[DD];
  int t = seq_len[b] - 1; t = min(max(t, 0), LL - 1);
  float v = 0.0f;
  if (tid < DD) v = x[((size_t)b * LL + t) * DD + tid];
  red[tid]  = (tid < DD) ? v : 0.0f;
  red2[tid] = (tid < DD) ? v * v : 0.0f;
  __syncthreads();
  for (int s = 64; s > 0; s >>= 1) {
    if (tid < s) { red[tid] += red[tid + s]; red2[tid] += red2[tid + s]; }
    __syncthreads();
  }
  float mean = red[0] / DD;
  float var  = fmaxf(red2[0] / DD - mean * mean, 0.0f);
  float rstd = rsqrtf(var + 1e-5f);
  float f = 0.0f;
  if (tid < DD) { f = (v - mean) * rstd * fn_g[tid] + fn_b[tid]; fbuf[tid] = f; }
  __syncthreads();
  red[tid] = (tid < DD) ? f * f : 0.0f;
  __syncthreads();
  for (int s = 64; s > 0; s >>= 1) {
    if (tid < s) red[tid] += red[tid + s];
    __syncthreads();
  }
  float rn = 1.0f / fmaxf(sqrtf(red[0]), 1e-12f);
  if (tid < DD) {
    fnorm[(size_t)b * DD + tid] = f * rn;
    float gacc = pr_b1[tid];
    for (int i = 0; i < DD; i++) gacc += fbuf[i] * pr_w1[i * DD + tid];
    h1[(size_t)b * DD + tid] = gelu_f(gacc);
  }
}

// ---------------------------------------------------------------------------
// K6: normalize proto rows -> transposed pnormT[k][c]
// ---------------------------------------------------------------------------
__global__ __launch_bounds__(128) void k_pnorm(
    const float* __restrict__ protos, float* __restrict__ pnormT) {
  int c = blockIdx.x, tid = threadIdx.x;
  __shared__ float red[128];
  float v = 0.0f;
  if (tid < DD) v = protos[(size_t)c * DD + tid];
  red[tid] = (tid < DD) ? v * v : 0.0f;
  __syncthreads();
  for (int s = 64; s > 0; s >>= 1) {
    if (tid < s) red[tid] += red[tid + s];
    __syncthreads();
  }
  float rn = 1.0f / fmaxf(sqrtf(red[0]), 1e-12f);
  if (tid < DD) pnormT[(size_t)tid * NLOC + c] = v * rn;
}

// ---------------------------------------------------------------------------
// K7: logits — 4 batch rows per block
// ---------------------------------------------------------------------------
__global__ __launch_bounds__(256) void k_logits(
    const float* __restrict__ h1, const float* __restrict__ fnorm,
    const float* __restrict__ pr_w2, const float* __restrict__ pr_b2,
    const float* __restrict__ pnormT, const float* __restrict__ temp,
    float* __restrict__ out) {
  int b0 = (blockIdx.x / 5) * 4, cb = blockIdx.x % 5;
  int tid = threadIdx.x;
  int c = cb * 256 + tid;
  __shared__ float h1s[4][DD], fns[4][DD];
  for (int i = tid; i < 4 * DD; i += 256) {
    int j = i / DD, k = i % DD;
    h1s[j][k] = h1[(size_t)(b0 + j) * DD + k];
    fns[j][k] = fnorm[(size_t)(b0 + j) * DD + k];
  }
  __syncthreads();
  if (c < NLOC) {
    float a1[4] = {0, 0, 0, 0}, a2[4] = {0, 0, 0, 0};
    for (int k = 0; k < DD; k++) {
      float w = pr_w2[(size_t)k * NLOC + c];
      float p = pnormT[(size_t)k * NLOC + c];
      #pragma unroll
      for (int j = 0; j < 4; j++) {
        a1[j] += h1s[j][k] * w;
        a2[j] += fns[j][k] * p;
      }
    }
    float pb = pr_b2[c];
    float tt = fminf(fmaxf(temp[0], 0.5f), 3.0f);
    #pragma unroll
    for (int j = 0; j < 4; j++)
      out[(size_t)(b0 + j) * NLOC + c] = (0.5f * (a1[j] + pb) + 7.5f * a2[j]) / tt;
  }
}

// ---------------------------------------------------------------------------
extern "C" void kernel_launch(void* const* d_in, const int* in_sizes, int n_in,
                              void* d_out, int out_size, void* d_ws, size_t ws_size,
                              hipStream_t stream) {
  const int* loc_seq   = (const int*)d_in[0];
  const int* user_seq  = (const int*)d_in[1];
  const int* wk_seq    = (const int*)d_in[2];
  const int* sm_seq    = (const int*)d_in[3];
  const int* dur_seq   = (const int*)d_in[4];
  const int* diff_seq  = (const int*)d_in[5];
  const int* seq_len   = (const int*)d_in[6];
  const float* loc_table = (const float*)d_in[7];
  const float* user_table= (const float*)d_in[8];
  const float* wk_table  = (const float*)d_in[9];
  const float* hr_table  = (const float*)d_in[10];
  const float* in_w   = (const float*)d_in[11];
  const float* in_b   = (const float*)d_in[12];
  const float* in_g   = (const float*)d_in[13];
  const float* in_be  = (const float*)d_in[14];
  const float* pos_emb= (const float*)d_in[15];
  const float* qkv_w  = (const float*)d_in[16];
  const float* proj_w = (const float*)d_in[17];
  const float* proj_b = (const float*)d_in[18];
  const float* rel_emb= (const float*)d_in[19];
  const float* n1_g   = (const float*)d_in[20];
  const float* n1_b   = (const float*)d_in[21];
  const float* ffn_w1 = (const float*)d_in[22];
  const float* ffn_b1 = (const float*)d_in[23];
  const float* ffn_w2 = (const float*)d_in[24];
  const float* ffn_b2 = (const float*)d_in[25];
  const float* n2_g   = (const float*)d_in[26];
  const float* n2_b   = (const float*)d_in[27];
  const float* fn_g   = (const float*)d_in[28];
  const float* fn_b   = (const float*)d_in[29];
  const float* pr_w1  = (const float*)d_in[30];
  const float* pr_b1  = (const float*)d_in[31];
  const float* pr_w2  = (const float*)d_in[32];
  const float* pr_b2  = (const float*)d_in[33];
  const float* protos = (const float*)d_in[34];
  const float* temp   = (const float*)d_in[35];
  float* out = (float*)d_out;

  float* x      = (float*)d_ws;
  float* o      = x + (size_t)BB * LL * DD;
  float* qkvo   = o + (size_t)BB * LL * DD;
  float* fnorm  = qkvo + (size_t)BB * 14400;
  float* h1     = fnorm + (size_t)BB * DD;
  float* pnormT = h1 + (size_t)BB * DD;
  float* relTg  = pnormT + (size_t)DD * NLOC;   // 3600 floats

  k_rprep<<<15, 256, 0, stream>>>(rel_emb, relTg);

  k_embed<<<BB * LL / 48, 256, 0, stream>>>(loc_seq, user_seq, wk_seq, sm_seq,
                                            dur_seq, diff_seq, loc_table,
                                            user_table, wk_table, hr_table,
                                            in_w, in_b, in_g, in_be, pos_emb, x);

  for (int l = 0; l < NLNUM; l++) {
    k_qkv<<<BB, 256, 0, stream>>>(x, qkv_w + (size_t)l * 80 * 240, qkvo);
    k_attn<<<BB * HH, 256, 0, stream>>>(qkvo, loc_seq,
                                        relTg + (size_t)l * 1200, o);
    k_pffn<<<BB * LL / 48, 256, 0, stream>>>(
        o, proj_w + (size_t)l * DD * DD, proj_b + (size_t)l * DD,
        n1_g + (size_t)l * DD, n1_b + (size_t)l * DD,
        ffn_w1 + (size_t)l * DD * DFF, ffn_b1 + (size_t)l * DFF,
        ffn_w2 + (size_t)l * DFF * DD, ffn_b2 + (size_t)l * DD,
        n2_g + (size_t)l * DD, n2_b + (size_t)l * DD, x);
  }

  k_pnorm<<<NLOC, 128, 0, stream>>>(protos, pnormT);
  k_final<<<BB, 128, 0, stream>>>(x, seq_len, fn_g, fn_b, pr_w1, pr_b1, fnorm, h1);
  k_logits<<<(BB / 4) * 5, 256, 0, stream>>>(h1, fnorm, pr_w2, pr_b2, pnormT, temp, out);
}